// Round 1
// baseline (910.619 us; speedup 1.0000x reference)
//
#include <hip/hip_runtime.h>
#include <stdint.h>

#define BATCH 32
#define SEQ   512
#define DM    512
#define NL    4
#define DSTATE 64
#define DI    1024   // D_INNER
#define NH    16
#define HD    64
#define PREDN 96
#define CDIM  1152   // DI + 2*DSTATE
#define CSEG  144    // CDIM/8
#define DPROJ 2192
#define XBW   1168   // xBC (1152) + dt (16) columns
#define NC    8      // chunks per sequence
#define EPSF  1e-5f

typedef float  f32x4  __attribute__((ext_vector_type(4)));
typedef __bf16 bf16x4 __attribute__((ext_vector_type(4)));
typedef __bf16 bf16x8 __attribute__((ext_vector_type(8)));

__device__ __forceinline__ float sigmoidf_(float x){ return 1.f/(1.f+__expf(-x)); }
__device__ __forceinline__ float siluf_(float x){ return x*sigmoidf_(x); }
__device__ __forceinline__ float softplusf_(float x){ return (x>20.f)?x:log1pf(__expf(x)); }

// direct global->LDS async copy, 16B per lane
__device__ __forceinline__ void gld16(const void* g, void* l){
  __builtin_amdgcn_global_load_lds((__attribute__((address_space(1))) void*)g,
                                   (__attribute__((address_space(3))) void*)l, 16, 0, 0);
}

// ---------------------------------------------------------------------------
// R9: 256x256-tile 8-phase GEMM for in_proj (T2 swizzle + T3/T4 counted vmcnt
// + T5 setprio).  8 waves (2M x 4N), BK=64, 128 KiB LDS double-buffer.
// Schedule (derived from region-death analysis, quadrant order
// (0,0),(0,1),(1,0),(1,1)):
//   phase reads (buf ct):  ph0: A0,B0  ph1: A0,B1  ph2: A1,B0  ph3: A1,B1
//   region death:          A0 after ph1, B0 after ph2, A1/B1 after ph3
//   stage: ph0 -> (t+1).A1 [buf^1]   ph1 -> (t+1).B1 [buf^1]
//          ph2 -> (t+2).A0 [buf]     ph3 -> (t+2).B0 [buf]
//   single s_waitcnt vmcnt(4) at end of ph3 (leaves the 2 newest half-tiles
//   in flight); raw s_barrier only, no vmcnt(0) drain in steady state.
// A-half q0: rows [q0*64,+64) U [128+q0*64,+64); B-half q1: seg*64+q1*32+[0,32).
// LDS col-blocks pre-swizzled at the GLOBAL source: physical block p at row r
// holds logical k-block p^(r&7)  (SQ_LDS_BANK_CONFLICT==0 in gemm128 with the
// same scheme).  Split epilogue (C / C2) identical semantics to gemm128.
// ---------------------------------------------------------------------------
__global__ __launch_bounds__(512,2) void gemm256(
    const __bf16* __restrict__ A, const __bf16* __restrict__ W,
    __bf16* __restrict__ C, __bf16* __restrict__ C2,
    int Nreal, int ldc, int ldc2, int splitN, int K)
{
  __shared__ __bf16 sm[2][2][256*64];   // [buf][A/B][row*64+col], 128 KiB
  const int tid  = threadIdx.x;
  const int m0   = blockIdx.x*256, n0 = blockIdx.y*256;  // row-tile fastest (XCD locality)
  const int lane = tid&63, wave = tid>>6;
  const int l15  = lane&15, quad = lane>>4;
  const int wm   = wave>>2, wn = wave&3;   // 2 x 4 wave grid
  const int rA   = wm*128,  rB = wn*64;
  const int nt   = K>>6;

  f32x4 acc[8][4];
  #pragma unroll
  for (int a=0;a<8;++a)
    #pragma unroll
    for (int b=0;b<4;++b) acc[a][b] = (f32x4){0,0,0,0};

  // stage A-half q0 of K-tile kt into buffer bsel (2 gld16 / thread)
  auto stA = [&](int bsel, int q0, int kt){
    __bf16* dst = &sm[bsel][0][0];
    const int k0 = kt*64;
    #pragma unroll
    for (int j=0;j<2;++j){
      const int s  = j*512 + tid;           // 0..1023
      const int rl = s>>3, pb = s&7;        // rl 0..127
      const int row = ((rl&64)<<1) + q0*64 + (rl&63);
      const int kc  = (pb ^ (row&7))<<3;    // pre-swizzled source k-block
      gld16(A + (size_t)(m0+row)*K + k0 + kc, dst + row*64 + pb*8);
    }
  };
  // stage B-half q1 of K-tile kt into buffer bsel
  auto stB = [&](int bsel, int q1, int kt){
    __bf16* dst = &sm[bsel][1][0];
    const int k0 = kt*64;
    #pragma unroll
    for (int j=0;j<2;++j){
      const int s  = j*512 + tid;
      const int rl = s>>3, pb = s&7;
      const int row = ((rl>>5)<<6) + q1*32 + (rl&31);
      const int kc  = (pb ^ (row&7))<<3;
      int gr = n0 + row; gr = gr < Nreal ? gr : Nreal-1;
      gld16(W + (size_t)gr*K + k0 + kc, dst + row*64 + pb*8);
    }
  };

  // ---- prologue: tile0 complete + tile1 A0,B0 (steady-state order) ----
  stA(0,0,0); stB(0,0,0); stA(0,1,0); stB(0,1,0);
  if (nt > 1){
    stA(1,0,1); stB(1,0,1);
    asm volatile("s_waitcnt vmcnt(4)" ::: "memory");   // tile0 landed
  } else {
    asm volatile("s_waitcnt vmcnt(0)" ::: "memory");
  }
  asm volatile("" ::: "memory");
  __builtin_amdgcn_s_barrier();
  asm volatile("" ::: "memory");

  for (int t=0; t<nt; ++t){
    const int ct = t&1, nb = ct^1;
    const __bf16* bA = &sm[ct][0][0];
    const __bf16* bB = &sm[ct][1][0];
    #pragma unroll
    for (int ph=0; ph<4; ++ph){
      const int q0 = ph>>1, q1 = ph&1;
      // ---- register subtile: 8 A + 4 B ds_read_b128 ----
      bf16x8 av[4][2], bv[2][2];
      #pragma unroll
      for (int j=0;j<4;++j){
        const int row = rA + q0*64 + j*16 + l15;
        #pragma unroll
        for (int kh=0;kh<2;++kh){
          const int pbk = ((kh*4+quad) ^ (row&7))<<3;
          av[j][kh] = *(const bf16x8*)&bA[row*64 + pbk];
        }
      }
      #pragma unroll
      for (int i=0;i<2;++i){
        const int row = rB + q1*32 + i*16 + l15;
        #pragma unroll
        for (int kh=0;kh<2;++kh){
          const int pbk = ((kh*4+quad) ^ (row&7))<<3;
          bv[i][kh] = *(const bf16x8*)&bB[row*64 + pbk];
        }
      }
      // ---- stage one half-tile (regions dead per schedule above) ----
      if      (ph==0){ if (t+1<nt) stA(nb,1,t+1); }
      else if (ph==1){ if (t+1<nt) stB(nb,1,t+1); }
      else if (ph==2){ if (t+2<nt) stA(ct,0,t+2); }
      else           { if (t+2<nt) stB(ct,0,t+2); }
      asm volatile("" ::: "memory");
      __builtin_amdgcn_s_barrier();            // lockstep: loads-in-flight vs MFMA
      asm volatile("" ::: "memory");
      __builtin_amdgcn_s_setprio(1);
      #pragma unroll
      for (int kh=0;kh<2;++kh)
        #pragma unroll
        for (int j=0;j<4;++j)
          #pragma unroll
          for (int i=0;i<2;++i)
            acc[q0*4+j][q1*2+i] = __builtin_amdgcn_mfma_f32_16x16x32_bf16(
                av[j][kh], bv[i][kh], acc[q0*4+j][q1*2+i], 0,0,0);
      __builtin_amdgcn_s_setprio(0);
      if (ph==3){
        if (t+2<nt) asm volatile("s_waitcnt vmcnt(4)" ::: "memory");  // counted, not drain
        else        asm volatile("s_waitcnt vmcnt(0)" ::: "memory");  // pipeline tail
      }
      asm volatile("" ::: "memory");
      __builtin_amdgcn_s_barrier();
      asm volatile("" ::: "memory");
    }
  }

  // ---- epilogue: bounce 256x256 bf16 tile through LDS, coalesced stores ----
  __bf16* sOut = &sm[0][0][0];                 // 128 KiB == 256*256 bf16
  #pragma unroll
  for (int mi=0;mi<8;++mi)
    #pragma unroll
    for (int ni=0;ni<4;++ni)
      #pragma unroll
      for (int r4=0;r4<4;++r4){
        const int row = rA + mi*16 + quad*4 + r4;
        const int col = rB + ni*16 + l15;
        const int g2  = (col>>3) ^ (row&31);   // 32-group XOR swizzle
        sOut[row*256 + g2*8 + (col&7)] = (__bf16)acc[mi][ni][r4];
      }
  asm volatile("" ::: "memory");
  __builtin_amdgcn_s_barrier();
  asm volatile("" ::: "memory");
  #pragma unroll
  for (int it=0; it<16; ++it){
    const int idx = it*512 + tid;
    const int row = idx>>5, gp = idx&31;
    const int gl  = gp ^ (row&31);
    bf16x8 v = *(const bf16x8*)&sOut[row*256 + gp*8];
    const int col0 = n0 + gl*8;
    if (col0 < Nreal){
      const int grow = m0 + row;
      if (col0 < splitN) *(bf16x8*)&C [(size_t)grow*ldc  + col0]          = v;
      else               *(bf16x8*)&C2[(size_t)grow*ldc2 + (col0-splitN)] = v;
    }
  }
}

// ---------------------------------------------------------------------------
// GEMM (B-transposed): bf16 MFMA, 128x128 tile, BK=64, global_load_lds,
// XOR-swizzled LDS, LDS-bounce bf16 epilogue.  Kept for out_proj (N=512:
// 256-tiles would leave half the CUs idle) and the fp32 final head.
// ---------------------------------------------------------------------------
template<typename TC>
__global__ __launch_bounds__(256) void gemm128(
    const __bf16* __restrict__ A, const __bf16* __restrict__ W,
    TC* __restrict__ C, TC* __restrict__ C2, const float* __restrict__ bias,
    int M, int Nreal, int ldc, int ldc2, int splitN, int K, int remapA)
{
  __shared__ __bf16 sAB[2*128*64];     // K-loop: sA | sW ; epilogue: 128x128 tile
  __bf16* sA = sAB;
  __bf16* sW = sAB + 128*64;
  const int tid  = threadIdx.x;
  const int m0   = blockIdx.x*128, n0 = blockIdx.y*128;   // row-tile fastest
  const int lane = tid&63, wave = tid>>6;
  const int l15  = lane&15, quad = lane>>4;
  const int wr   = (wave>>1)*64, wc = (wave&1)*64;
  f32x4 acc[4][4];
  #pragma unroll
  for (int a=0;a<4;++a)
    #pragma unroll
    for (int b=0;b<4;++b) acc[a][b] = (f32x4){0,0,0,0};

  for (int k0=0; k0<K; k0+=64){
    #pragma unroll
    for (int j=0;j<4;++j){
      const int f = j*256 + tid;
      const int r = f>>3;
      const int kc = (((f&7) ^ (r&7)))*8;      // XOR-swizzled source col-block
      int ga = m0 + r;
      if (remapA){ int bb = ga/PREDN; ga = bb*SEQ + (SEQ-PREDN) + (ga - bb*PREDN); }
      gld16(A + (size_t)ga*K + k0 + kc, &sA[f*8]);
      int rb = n0 + r; rb = rb < Nreal ? rb : (Nreal-1);
      gld16(W + (size_t)rb*K + k0 + kc, &sW[f*8]);
    }
    __syncthreads();
    #pragma unroll
    for (int kk=0; kk<64; kk+=32){
      const int kcb = (kk>>3) + quad;          // logical col-block 0..7
      bf16x8 av[4], bv[4];
      #pragma unroll
      for (int mi=0;mi<4;++mi){
        const int row = wr+mi*16+l15;
        av[mi] = *(const bf16x8*)&sA[row*64 + ((kcb ^ (row&7))<<3)];
      }
      #pragma unroll
      for (int ni=0;ni<4;++ni){
        const int row = wc+ni*16+l15;
        bv[ni] = *(const bf16x8*)&sW[row*64 + ((kcb ^ (row&7))<<3)];
      }
      #pragma unroll
      for (int mi=0;mi<4;++mi)
        #pragma unroll
        for (int ni=0;ni<4;++ni)
          acc[mi][ni] = __builtin_amdgcn_mfma_f32_16x16x32_bf16(av[mi],bv[ni],acc[mi][ni],0,0,0);
    }
    __syncthreads();
  }

  if constexpr (sizeof(TC)==2){
    // ---- bf16 epilogue: bounce tile through LDS, coalesced vector stores ----
    #pragma unroll
    for (int mi=0;mi<4;++mi)
      #pragma unroll
      for (int ni=0;ni<4;++ni)
        #pragma unroll
        for (int r4=0;r4<4;++r4){
          const int row = wr+mi*16+quad*4+r4;
          const int col = wc+ni*16+l15;
          const int g2  = (col>>3) ^ (row&15);        // swizzled 8-col group
          sAB[row*128 + g2*8 + (col&7)] = (__bf16)acc[mi][ni][r4];
        }
    __syncthreads();
    #pragma unroll
    for (int it=0; it<8; ++it){
      const int idx = it*256 + tid;
      const int row = idx>>4, g = idx&15;
      const int g2 = g ^ (row&15);
      bf16x8 v = *(const bf16x8*)&sAB[row*128 + g2*8];
      const int col0 = n0 + g*8;
      if (col0 < Nreal){
        const int grow = m0 + row;
        if (col0 < splitN) *(bf16x8*)&C [(size_t)grow*ldc  + col0]          = v;
        else               *(bf16x8*)&C2[(size_t)grow*ldc2 + (col0-splitN)] = v;
      }
    }
  } else {
    // ---- fp32 epilogue (final head): per-element + bias ----
    #pragma unroll
    for (int ni=0;ni<4;++ni){
      const int col = n0 + wc + ni*16 + l15;
      if (col < Nreal){
        const float badd = bias ? bias[col] : 0.f;
        #pragma unroll
        for (int mi=0;mi<4;++mi){
          #pragma unroll
          for (int r4=0;r4<4;++r4){
            const int row = m0 + wr + mi*16 + quad*4 + r4;
            C[(size_t)row*ldc + col] = (TC)(acc[mi][ni][r4] + badd);
          }
        }
      }
    }
  }
}

// ---------------------------------------------------------------------------
// merged fp32->bf16 casts: 4 (src,dst) regions, one launch. n* in float4 units.
// ---------------------------------------------------------------------------
__global__ __launch_bounds__(256) void cast4_k(
    const float* __restrict__ s0, __bf16* __restrict__ d0, int n0,
    const float* __restrict__ s1, __bf16* __restrict__ d1, int n1,
    const float* __restrict__ s2, __bf16* __restrict__ d2, int n2,
    const float* __restrict__ s3, __bf16* __restrict__ d3, int n3)
{
  int i = blockIdx.x*256 + threadIdx.x;
  const float* s; __bf16* d;
  if (i < n0){ s=s0; d=d0; }
  else if ((i-=n0) < n1){ s=s1; d=d1; }
  else if ((i-=n1) < n2){ s=s2; d=d2; }
  else if ((i-=n2) < n3){ s=s3; d=d3; }
  else return;
  float4 v = ((const float4*)s)[i];
  bf16x4 o;
  o[0]=(__bf16)v.x; o[1]=(__bf16)v.y; o[2]=(__bf16)v.z; o[3]=(__bf16)v.w;
  ((bf16x4*)d)[i] = o;
}

// ---------------------------------------------------------------------------
// Causal depthwise conv (width 4) + bias + SiLU, 8 channels per thread.
// ---------------------------------------------------------------------------
__global__ __launch_bounds__(256) void conv_silu_k(
    const __bf16* __restrict__ xbw, const float* __restrict__ cw,
    const float* __restrict__ cb, __bf16* __restrict__ xout,
    __bf16* __restrict__ bcout)
{
  int idx = blockIdx.x*256 + threadIdx.x;
  if (idx >= BATCH*SEQ*CSEG) return;
  const int seg = idx % CSEG;
  const int bt  = idx / CSEG;
  const int t = bt % SEQ, b = bt / SEQ;
  const int d0 = seg*8;
  const __bf16* src = xbw + ((size_t)b*SEQ + t)*XBW + d0;
  bf16x8 z8;
  #pragma unroll
  for (int e=0;e<8;++e) z8[e]=(__bf16)0.f;
  bf16x8 x3 = *(const bf16x8*)src;
  bf16x8 x2 = (t>=1)? *(const bf16x8*)(src -   XBW) : z8;
  bf16x8 x1 = (t>=2)? *(const bf16x8*)(src - 2*XBW) : z8;
  bf16x8 x0 = (t>=3)? *(const bf16x8*)(src - 3*XBW) : z8;
  const float4* w4  = (const float4*)(cw + (size_t)d0*4);
  const float4* cb4 = (const float4*)(cb + d0);
  float4 cbl = cb4[0], cbh = cb4[1];
  bf16x8 o;
  #pragma unroll
  for (int e=0;e<8;++e){
    float4 w = w4[e];
    float acc = (e<4 ? (&cbl.x)[e] : (&cbh.x)[e-4])
              + w.x*(float)x0[e] + w.y*(float)x1[e]
              + w.z*(float)x2[e] + w.w*(float)x3[e];
    o[e] = (__bf16)siluf_(acc);
  }
  if (d0 < DI) *(bf16x8*)(xout  + ((size_t)b*SEQ+t)*DI  + d0)       = o;
  else         *(bf16x8*)(bcout + ((size_t)b*SEQ+t)*128 + (d0-DI))  = o;
}

// ---------------------------------------------------------------------------
// Fused SSD: one block per (b,h). sS aliases sB (dead after mm1; extra
// barrier between mm1 and mask-write) -> LDS 50.2 KB -> 3 blocks/CU.
// ---------------------------------------------------------------------------
__global__ __launch_bounds__(256) void ssd_fused_k(
    const __bf16* __restrict__ bc,
    __bf16* __restrict__ xy,
    const __bf16* __restrict__ xbw,
    const float* __restrict__ dtb_, const float* __restrict__ alog_,
    const float* __restrict__ dp_)
{
  __shared__ __bf16 sPool[5*64*72];
  __bf16* sB   = sPool;                // aliased with sS (sB dead after mm1)
  __bf16* sS   = sPool;
  __bf16* sC   = sPool + 1*64*72;
  __bf16* sXT  = sPool + 2*64*72;
  __bf16* sBwT = sPool + 3*64*72;
  __bf16* sHT  = sPool + 4*64*72;
  __shared__ float sCS[SEQ], sDT[SEQ];
  const int bid = blockIdx.x;
  const int h = bid & 15, b = bid >> 4;
  const int tid = threadIdx.x, wave = tid>>6, lane = tid&63;
  const int l15 = lane&15, quad = lane>>4;
  const int wm = (wave>>1)*32, wn = (wave&1)*32;

  const float Ah  = -__expf(alog_[h]);
  const float dtb = dtb_[h];
  const float Dh  = dp_[h];

  for (int t = tid; t < SEQ; t += 256){
    float raw = (float)xbw[((size_t)b*SEQ + t)*XBW + CDIM + h];
    float dt = softplusf_(raw + dtb);
    sDT[t] = dt;
    sCS[t] = dt*Ah;
  }
  __syncthreads();
  for (int ch = wave; ch < NC; ch += 4){
    float s = sCS[ch*64 + lane];
    #pragma unroll
    for (int off=1; off<64; off<<=1){
      float v = __shfl_up(s, off);
      if (lane >= off) s += v;
    }
    sCS[ch*64 + lane] = s;
  }
  __syncthreads();

  f32x4 run[2][2];
  #pragma unroll
  for (int a=0;a<2;++a)
    #pragma unroll
    for (int d=0;d<2;++d) run[a][d] = (f32x4){0,0,0,0};

  for (int c = 0; c < NC; ++c){
    const int t0 = c*64;
    {
      const int r = tid>>2, seg = (tid&3)*16;
      const __bf16* row = bc + ((size_t)b*SEQ + t0 + r)*128;
      bf16x8 vb0 = *(const bf16x8*)(row + seg);
      bf16x8 vb1 = *(const bf16x8*)(row + seg + 8);
      bf16x8 vc0 = *(const bf16x8*)(row + 64 + seg);
      bf16x8 vc1 = *(const bf16x8*)(row + 64 + seg + 8);
      *(bf16x8*)&sB[r*72+seg]   = vb0;
      *(bf16x8*)&sB[r*72+seg+8] = vb1;
      *(bf16x8*)&sC[r*72+seg]   = vc0;
      *(bf16x8*)&sC[r*72+seg+8] = vc1;
      const float w = __expf(sCS[t0+63] - sCS[t0+r]) * sDT[t0+r];  // <=0 exp
      #pragma unroll
      for (int e=0;e<8;++e){
        sBwT[(seg+e)*72 + r]   = (__bf16)(w*(float)vb0[e]);
        sBwT[(seg+8+e)*72 + r] = (__bf16)(w*(float)vb1[e]);
      }
      const __bf16* xrow = xy + ((size_t)b*SEQ + t0 + r)*DI + h*64;
      bf16x8 vx0 = *(const bf16x8*)(xrow + seg);
      bf16x8 vx1 = *(const bf16x8*)(xrow + seg + 8);
      #pragma unroll
      for (int e=0;e<8;++e){
        sXT[(seg+e)*72 + r]   = vx0[e];
        sXT[(seg+8+e)*72 + r] = vx1[e];
      }
    }
    __syncthreads();

    f32x4 aS[2][2];
    #pragma unroll
    for (int a=0;a<2;++a)
      #pragma unroll
      for (int d=0;d<2;++d) aS[a][d] = (f32x4){0,0,0,0};
    #pragma unroll
    for (int kk=0; kk<64; kk+=32){
      const int kf = kk + quad*8;
      bf16x8 a0 = *(const bf16x8*)&sC[(wm+l15)*72+kf];
      bf16x8 a1 = *(const bf16x8*)&sC[(wm+16+l15)*72+kf];
      bf16x8 b0 = *(const bf16x8*)&sB[(wn+l15)*72+kf];
      bf16x8 b1 = *(const bf16x8*)&sB[(wn+16+l15)*72+kf];
      aS[0][0] = __builtin_amdgcn_mfma_f32_16x16x32_bf16(a0,b0,aS[0][0],0,0,0);
      aS[0][1] = __builtin_amdgcn_mfma_f32_16x16x32_bf16(a0,b1,aS[0][1],0,0,0);
      aS[1][0] = __builtin_amdgcn_mfma_f32_16x16x32_bf16(a1,b0,aS[1][0],0,0,0);
      aS[1][1] = __builtin_amdgcn_mfma_f32_16x16x32_bf16(a1,b1,aS[1][1],0,0,0);
    }
    __syncthreads();   // all waves done reading sB before sS(=sB) is written

    #pragma unroll
    for (int mi=0;mi<2;++mi)
      #pragma unroll
      for (int ni=0;ni<2;++ni)
        #pragma unroll
        for (int r4=0;r4<4;++r4){
          const int i = wm+mi*16+quad*4+r4, j = wn+ni*16+l15;
          float ed = __expf(fminf(sCS[t0+i]-sCS[t0+j], 0.f)) * sDT[t0+j];
          float v = aS[mi][ni][r4]*ed;
          sS[i*72+j] = (__bf16)((j<=i)? v : 0.f);
          sHT[j*72+i] = (__bf16)run[mi][ni][r4];   // [p][n]
        }
    __syncthreads();

    f32x4 aY[2][2], aH[2][2], aYi[2][2];
    #pragma unroll
    for (int a=0;a<2;++a)
      #pragma unroll
      for (int d=0;d<2;++d){
        aY[a][d]=(f32x4){0,0,0,0}; aH[a][d]=(f32x4){0,0,0,0};
        aYi[a][d]=(f32x4){0,0,0,0};
      }
    #pragma unroll
    for (int kk=0; kk<64; kk+=32){
      const int kf = kk + quad*8;
      bf16x8 b0 = *(const bf16x8*)&sXT[(wn+l15)*72+kf];
      bf16x8 b1 = *(const bf16x8*)&sXT[(wn+16+l15)*72+kf];
      bf16x8 s0 = *(const bf16x8*)&sS[(wm+l15)*72+kf];
      bf16x8 s1 = *(const bf16x8*)&sS[(wm+16+l15)*72+kf];
      bf16x8 w0 = *(const bf16x8*)&sBwT[(wm+l15)*72+kf];
      bf16x8 w1 = *(const bf16x8*)&sBwT[(wm+16+l15)*72+kf];
      bf16x8 c0 = *(const bf16x8*)&sC[(wm+l15)*72+kf];
      bf16x8 c1 = *(const bf16x8*)&sC[(wm+16+l15)*72+kf];
      bf16x8 h0 = *(const bf16x8*)&sHT[(wn+l15)*72+kf];
      bf16x8 h1 = *(const bf16x8*)&sHT[(wn+16+l15)*72+kf];
      aY[0][0] = __builtin_amdgcn_mfma_f32_16x16x32_bf16(s0,b0,aY[0][0],0,0,0);
      aY[0][1] = __builtin_amdgcn_mfma_f32_16x16x32_bf16(s0,b1,aY[0][1],0,0,0);
      aY[1][0] = __builtin_amdgcn_mfma_f32_16x16x32_bf16(s1,b0,aY[1][0],0,0,0);
      aY[1][1] = __builtin_amdgcn_mfma_f32_16x16x32_bf16(s1,b1,aY[1][1],0,0,0);
      aH[0][0] = __builtin_amdgcn_mfma_f32_16x16x32_bf16(w0,b0,aH[0][0],0,0,0);
      aH[0][1] = __builtin_amdgcn_mfma_f32_16x16x32_bf16(w0,b1,aH[0][1],0,0,0);
      aH[1][0] = __builtin_amdgcn_mfma_f32_16x16x32_bf16(w1,b0,aH[1][0],0,0,0);
      aH[1][1] = __builtin_amdgcn_mfma_f32_16x16x32_bf16(w1,b1,aH[1][1],0,0,0);
      aYi[0][0] = __builtin_amdgcn_mfma_f32_16x16x32_bf16(c0,h0,aYi[0][0],0,0,0);
      aYi[0][1] = __builtin_amdgcn_mfma_f32_16x16x32_bf16(c0,h1,aYi[0][1],0,0,0);
      aYi[1][0] = __builtin_amdgcn_mfma_f32_16x16x32_bf16(c1,h0,aYi[1][0],0,0,0);
      aYi[1][1] = __builtin_amdgcn_mfma_f32_16x16x32_bf16(c1,h1,aYi[1][1],0,0,0);
    }

    const float lam = __expf(sCS[t0+63]);
    #pragma unroll
    for (int mi=0;mi<2;++mi)
      #pragma unroll
      for (int ni=0;ni<2;++ni)
        #pragma unroll
        for (int r4=0;r4<4;++r4){
          const int i = wm+mi*16+quad*4+r4;
          const int p = wn+ni*16+l15;
          const float xval = (float)sXT[p*72 + i];
          const float e2 = __expf(sCS[t0+i]);    // <=1 (cs<=0)
          const float yv = aY[mi][ni][r4] + Dh*xval + e2*aYi[mi][ni][r4];
          xy[((size_t)b*SEQ + t0 + i)*DI + h*64 + p] = (__bf16)yv;
          run[mi][ni][r4] = run[mi][ni][r4]*lam + aH[mi][ni][r4];
        }
    __syncthreads();
  }
}

// ---------------------------------------------------------------------------
__global__ __launch_bounds__(256) void gate_rms_k(
    __bf16* __restrict__ y, const __bf16* __restrict__ z, const float* __restrict__ nw)
{
  __shared__ float red[4];
  const int tid = threadIdx.x;
  const int sub = tid>>7;
  const int off = (tid&127)*8;
  const size_t row = (size_t)blockIdx.x*2 + sub;
  __bf16* yrow = y + row*DI;
  const __bf16* zrow = z + row*DI;
  bf16x8 yv = *(const bf16x8*)(yrow+off);
  bf16x8 zv = *(const bf16x8*)(zrow+off);
  float u[8]; float ss = 0.f;
  #pragma unroll
  for (int e=0;e<8;++e){
    float uu = (float)yv[e]*siluf_((float)zv[e]);
    u[e]=uu; ss += uu*uu;
  }
  #pragma unroll
  for (int o=32;o;o>>=1) ss += __shfl_xor(ss,o);
  if ((tid&63)==0) red[tid>>6] = ss;
  __syncthreads();
  ss = red[sub*2] + red[sub*2+1];
  const float sc = rsqrtf(ss*(1.f/DI) + EPSF);
  const float4* nw4 = (const float4*)(nw + off);
  float4 n0 = nw4[0], n1 = nw4[1];
  bf16x8 o;
  #pragma unroll
  for (int e=0;e<8;++e)
    o[e] = (__bf16)(u[e]*sc*(e<4 ? (&n0.x)[e] : (&n1.x)[e-4]));
  *(bf16x8*)(yrow+off) = o;
}

// ---------------------------------------------------------------------------
__global__ __launch_bounds__(256) void add_ln_k(
    const __bf16* __restrict__ tmp, __bf16* __restrict__ resio,
    const float* __restrict__ w, const float* __restrict__ bb)
{
  const int tid = threadIdx.x, lane = tid&63;
  const size_t row = (size_t)blockIdx.x*4 + (tid>>6);
  const int off = lane*8;
  const __bf16* trow = tmp + row*DM;
  __bf16* rrow = resio + row*DM;
  bf16x8 tv = *(const bf16x8*)(trow+off);
  bf16x8 rv = *(const bf16x8*)(rrow+off);
  float v[8]; float s = 0.f;
  #pragma unroll
  for (int e=0;e<8;++e){ v[e]=(float)tv[e]+(float)rv[e]; s += v[e]; }
  #pragma unroll
  for (int o=32;o;o>>=1) s += __shfl_xor(s,o);
  const float mean = s*(1.f/DM);
  float q = 0.f;
  #pragma unroll
  for (int e=0;e<8;++e){ v[e]-=mean; q += v[e]*v[e]; }
  #pragma unroll
  for (int o=32;o;o>>=1) q += __shfl_xor(q,o);
  const float rstd = rsqrtf(q*(1.f/DM) + EPSF);
  const float4* w4 = (const float4*)(w + off);
  const float4* b4 = (const float4*)(bb + off);
  float4 w0=w4[0], w1=w4[1], b0=b4[0], b1=b4[1];
  bf16x8 o8;
  #pragma unroll
  for (int e=0;e<8;++e){
    float we = e<4 ? (&w0.x)[e] : (&w1.x)[e-4];
    float be = e<4 ? (&b0.x)[e] : (&b1.x)[e-4];
    o8[e] = (__bf16)(v[e]*rstd*we + be);
  }
  *(bf16x8*)(rrow+off) = o8;
}

// ---------------------------------------------------------------------------
extern "C" void kernel_launch(void* const* d_in, const int* in_sizes, int n_in,
                              void* d_out, int out_size, void* d_ws, size_t ws_size,
                              hipStream_t stream)
{
  const float* x         = (const float*)d_in[0];
  const float* in_proj_w = (const float*)d_in[1];
  const float* conv_w    = (const float*)d_in[2];
  const float* conv_b    = (const float*)d_in[3];
  const float* dt_bias   = (const float*)d_in[4];
  const float* A_log     = (const float*)d_in[5];
  const float* Dp        = (const float*)d_in[6];
  const float* norm_w    = (const float*)d_in[7];
  const float* out_proj_w= (const float*)d_in[8];
  const float* ln_w      = (const float*)d_in[9];
  const float* ln_b      = (const float*)d_in[10];
  const float* final_w   = (const float*)d_in[11];
  const float* final_b   = (const float*)d_in[12];
  float* out = (float*)d_out;

  const size_t ROWS = (size_t)BATCH*SEQ;        // 16384
  __bf16* wbf_in  = (__bf16*)d_ws;
  __bf16* wbf_out = wbf_in  + (size_t)NL*DPROJ*DM;
  __bf16* wbf_fin = wbf_out + (size_t)NL*DM*DI;
  __bf16* zbuf    = wbf_fin + (size_t)DM*DM;
  __bf16* xbw     = zbuf    + ROWS*DI;
  __bf16* ybuf    = xbw     + ROWS*XBW;
  __bf16* bcb     = ybuf    + ROWS*DI;
  __bf16* xcur    = bcb     + ROWS*128;
  __bf16* tmp  = xbw;     // alias: xbw dead after ssd_fused reads dt

  {
    int n1 = NL*DPROJ*DM/4, n2 = NL*DM*DI/4, n3 = DM*DM/4, n4 = (int)(ROWS*DM/4);
    int tot = n1+n2+n3+n4;
    cast4_k<<<(tot+255)/256, 256, 0, stream>>>(
        in_proj_w, wbf_in, n1, out_proj_w, wbf_out, n2,
        final_w, wbf_fin, n3, x, xcur, n4);
  }

  const int convTotal = BATCH*SEQ*CSEG;
  const int BIGN = 1<<30;

  for (int l=0; l<NL; ++l){
    const __bf16* wl = wbf_in + (size_t)l*DPROJ*DM;
    // in_proj: 256x256 8-phase pipelined GEMM (grid x = row-tile, XCD locality)
    gemm256<<<dim3((int)(ROWS/256), (DPROJ+255)/256), 512, 0, stream>>>(
        xcur, wl, zbuf, xbw, DPROJ, DI, XBW, DI, DM);
    conv_silu_k<<<(convTotal+255)/256, 256, 0, stream>>>(
        xbw, conv_w + (size_t)l*CDIM*4, conv_b + (size_t)l*CDIM, ybuf, bcb);
    ssd_fused_k<<<BATCH*NH, 256, 0, stream>>>(
        bcb, ybuf, xbw, dt_bias + l*NH, A_log + l*NH, Dp + l*NH);
    gate_rms_k<<<(int)(ROWS/2), 256, 0, stream>>>(ybuf, zbuf, norm_w + (size_t)l*DI);
    gemm128<__bf16><<<dim3((int)(ROWS/128), DM/128), 256, 0, stream>>>(
        ybuf, wbf_out + (size_t)l*DM*DI, tmp, tmp, nullptr, (int)ROWS, DM, DM, DM, BIGN, DI, 0);
    add_ln_k<<<(int)(ROWS/4), 256, 0, stream>>>(tmp, xcur, ln_w + l*DM, ln_b + l*DM);
  }
  // final head: A-rows remapped to the last PREDN timesteps of xcur
  gemm128<float><<<dim3((BATCH*PREDN)/128, DM/128), 256, 0, stream>>>(
      xcur, wbf_fin, out, out, final_b, BATCH*PREDN, DM, DM, DM, BIGN, DM, 1);
}

// Round 3
// 894.234 us; speedup vs baseline: 1.0183x; 1.0183x over previous
//
#include <hip/hip_runtime.h>
#include <stdint.h>

#define BATCH 32
#define SEQ   512
#define DM    512
#define NL    4
#define DSTATE 64
#define DI    1024   // D_INNER
#define NH    16
#define HD    64
#define PREDN 96
#define CDIM  1152   // DI + 2*DSTATE
#define CSEG  144    // CDIM/8
#define DPROJ 2192
#define XBW   1168   // xBC (1152) + dt (16) columns
#define NC    8      // chunks per sequence
#define EPSF  1e-5f

typedef float  f32x4  __attribute__((ext_vector_type(4)));
typedef __bf16 bf16x4 __attribute__((ext_vector_type(4)));
typedef __bf16 bf16x8 __attribute__((ext_vector_type(8)));

__device__ __forceinline__ float sigmoidf_(float x){ return 1.f/(1.f+__expf(-x)); }
__device__ __forceinline__ float siluf_(float x){ return x*sigmoidf_(x); }
__device__ __forceinline__ float softplusf_(float x){ return (x>20.f)?x:log1pf(__expf(x)); }

// direct global->LDS async copy, 16B per lane
__device__ __forceinline__ void gld16(const void* g, void* l){
  __builtin_amdgcn_global_load_lds((__attribute__((address_space(1))) void*)g,
                                   (__attribute__((address_space(3))) void*)l, 16, 0, 0);
}

// ---------------------------------------------------------------------------
// R10b (R10 resubmit after infra failure; cosmetic hardening only):
// 256x256 tile, 2 phases per K-tile (minimum-LDS-traffic schedule).
// R9 post-mortem: 12 ds_read_b128/wave/phase (96 KiB/CU/phase vs 256 B/cyc
// port) made the kernel LDS-read-bound at 20% MfmaUtil.  Fix: read each
// fragment ONCE per K-tile -> 24 reads/tile/wave (8 B held in regs across
// both phases; A-quadrant streamed 1:1 into the MFMA cluster), and halve
// the barrier count (4/tile).
// Schedule (region-death verified):
//   P0: read B0..B3 (8 ds_read) | stage (t+1).{A1,B1} -> nb | bar |
//       stream A0 frags + 32 MFMA | bar
//   P1: stage (t+2).{A0,B0} -> ct | bar | stream A1 frags + 32 MFMA |
//       vmcnt(4) (counted, leaves t+2 halves in flight) | bar
// Region deaths in ct: A0@P0, B0/B1 reads complete by P0-mid barrier
// (consumed by P0 MFMAs), A1@P1; all reads of a region complete before the
// phase-end barrier that precedes any stage targeting it.  LDS col-blocks
// pre-swizzled at the GLOBAL source: physical block p at row r holds
// logical k-block p^(r&7)  (SQ_LDS_BANK_CONFLICT==0 measured).
// ---------------------------------------------------------------------------
__global__ __launch_bounds__(512,2) void gemm256(
    const __bf16* __restrict__ A, const __bf16* __restrict__ W,
    __bf16* __restrict__ C, __bf16* __restrict__ C2,
    int Nreal, int ldc, int ldc2, int splitN, int K)
{
  __shared__ __bf16 sm[2][2][256*64];   // [buf][A/B][row*64+col], 128 KiB
  const int tid  = threadIdx.x;
  const int m0   = blockIdx.x*256, n0 = blockIdx.y*256;  // row-tile fastest (XCD locality)
  const int lane = tid&63, wave = tid>>6;
  const int l15  = lane&15, quad = lane>>4;
  const int wm   = wave>>2, wn = wave&3;   // 2 x 4 wave grid
  const int rA   = wm*128,  rB = wn*64;
  const int nt   = K>>6;

  f32x4 acc[8][4];
  #pragma unroll
  for (int a=0;a<8;++a)
    #pragma unroll
    for (int b=0;b<4;++b) acc[a][b] = (f32x4){0,0,0,0};

  // stage A-half q0 of K-tile kt into buffer bsel (2 gld16 / thread)
  // A-half q0 = rows with bit6==q0:  {q0*64..+64} U {128+q0*64..+64}
  auto stA = [&](int bsel, int q0, int kt){
    __bf16* dst = &sm[bsel][0][0];
    const int k0 = kt*64;
    #pragma unroll
    for (int j=0;j<2;++j){
      const int s  = j*512 + tid;           // 0..1023
      const int rl = s>>3, pb = s&7;        // rl 0..127
      const int row = ((rl&64)<<1) + q0*64 + (rl&63);
      const int kc  = (pb ^ (row&7))<<3;    // pre-swizzled source k-block
      gld16(A + (size_t)(m0+row)*K + k0 + kc, dst + row*64 + pb*8);
    }
  };
  // stage B-half q1 (rows with bit5==q1) of K-tile kt into buffer bsel
  auto stB = [&](int bsel, int q1, int kt){
    __bf16* dst = &sm[bsel][1][0];
    const int k0 = kt*64;
    #pragma unroll
    for (int j=0;j<2;++j){
      const int s  = j*512 + tid;
      const int rl = s>>3, pb = s&7;
      const int row = ((rl>>5)<<6) + q1*32 + (rl&31);
      const int kc  = (pb ^ (row&7))<<3;
      int gr = n0 + row; gr = gr < Nreal ? gr : Nreal-1;
      gld16(W + (size_t)gr*K + k0 + kc, dst + row*64 + pb*8);
    }
  };

  // ---- prologue: tile0 complete + tile1 {A0,B0} (steady-state order) ----
  stA(0,0,0); stB(0,0,0); stA(0,1,0); stB(0,1,0);
  if (nt > 1){
    stA(1,0,1); stB(1,0,1);
    asm volatile("s_waitcnt vmcnt(4)" ::: "memory");   // tile0 landed
  } else {
    asm volatile("s_waitcnt vmcnt(0)" ::: "memory");
  }
  __builtin_amdgcn_s_barrier();
  asm volatile("" ::: "memory");

  for (int t=0; t<nt; ++t){
    const int ct = t&1, nb = ct^1;
    const __bf16* bA = &sm[ct][0][0];
    const __bf16* bB = &sm[ct][1][0];

    // ---- phase 0: B frags once per tile (held through both phases) ----
    bf16x8 bfr[4][2];
    #pragma unroll
    for (int i=0;i<4;++i){
      const int row = rB + i*16 + l15;
      #pragma unroll
      for (int kh=0;kh<2;++kh)
        bfr[i][kh] = *(const bf16x8*)&bB[row*64 + (((kh*4+quad) ^ (row&7))<<3)];
    }
    if (t+1<nt){ stA(nb,1,t+1); stB(nb,1,t+1); }
    asm volatile("" ::: "memory");
    __builtin_amdgcn_s_barrier();
    asm volatile("" ::: "memory");
    __builtin_amdgcn_s_setprio(1);
    {
      // stream A0 quadrant: 2 ds_read -> 8 MFMA, hand-pipelined
      const int row0 = rA + 0*16 + l15;
      bf16x8 a0 = *(const bf16x8*)&bA[row0*64 + (((0*4+quad) ^ (row0&7))<<3)];
      bf16x8 a1 = *(const bf16x8*)&bA[row0*64 + (((1*4+quad) ^ (row0&7))<<3)];
      #pragma unroll
      for (int j=0;j<4;++j){
        bf16x8 pn0 = a0, pn1 = a1;
        if (j<3){
          const int rown = rA + (j+1)*16 + l15;
          pn0 = *(const bf16x8*)&bA[rown*64 + (((0*4+quad) ^ (rown&7))<<3)];
          pn1 = *(const bf16x8*)&bA[rown*64 + (((1*4+quad) ^ (rown&7))<<3)];
        }
        #pragma unroll
        for (int i=0;i<4;++i)
          acc[j][i] = __builtin_amdgcn_mfma_f32_16x16x32_bf16(a0, bfr[i][0], acc[j][i],0,0,0);
        #pragma unroll
        for (int i=0;i<4;++i)
          acc[j][i] = __builtin_amdgcn_mfma_f32_16x16x32_bf16(a1, bfr[i][1], acc[j][i],0,0,0);
        a0 = pn0; a1 = pn1;
      }
    }
    __builtin_amdgcn_s_setprio(0);
    asm volatile("" ::: "memory");
    __builtin_amdgcn_s_barrier();
    asm volatile("" ::: "memory");

    // ---- phase 1: reuse B from regs, stream A1 quadrant ----
    if (t+2<nt){ stA(ct,0,t+2); stB(ct,0,t+2); }
    asm volatile("" ::: "memory");
    __builtin_amdgcn_s_barrier();
    asm volatile("" ::: "memory");
    __builtin_amdgcn_s_setprio(1);
    {
      const int row0 = rA + 64 + 0*16 + l15;
      bf16x8 a0 = *(const bf16x8*)&bA[row0*64 + (((0*4+quad) ^ (row0&7))<<3)];
      bf16x8 a1 = *(const bf16x8*)&bA[row0*64 + (((1*4+quad) ^ (row0&7))<<3)];
      #pragma unroll
      for (int j=0;j<4;++j){
        bf16x8 pn0 = a0, pn1 = a1;
        if (j<3){
          const int rown = rA + 64 + (j+1)*16 + l15;
          pn0 = *(const bf16x8*)&bA[rown*64 + (((0*4+quad) ^ (rown&7))<<3)];
          pn1 = *(const bf16x8*)&bA[rown*64 + (((1*4+quad) ^ (rown&7))<<3)];
        }
        #pragma unroll
        for (int i=0;i<4;++i)
          acc[4+j][i] = __builtin_amdgcn_mfma_f32_16x16x32_bf16(a0, bfr[i][0], acc[4+j][i],0,0,0);
        #pragma unroll
        for (int i=0;i<4;++i)
          acc[4+j][i] = __builtin_amdgcn_mfma_f32_16x16x32_bf16(a1, bfr[i][1], acc[4+j][i],0,0,0);
        a0 = pn0; a1 = pn1;
      }
    }
    __builtin_amdgcn_s_setprio(0);
    if (t+2<nt) asm volatile("s_waitcnt vmcnt(4)" ::: "memory");  // counted, not drain
    else        asm volatile("s_waitcnt vmcnt(0)" ::: "memory");  // pipeline tail
    asm volatile("" ::: "memory");
    __builtin_amdgcn_s_barrier();
    asm volatile("" ::: "memory");
  }

  // ---- epilogue: bounce 256x256 bf16 tile through LDS, coalesced stores ----
  __bf16* sOut = &sm[0][0][0];                 // 128 KiB == 256*256 bf16
  #pragma unroll
  for (int mi=0;mi<8;++mi)
    #pragma unroll
    for (int ni=0;ni<4;++ni)
      #pragma unroll
      for (int r4=0;r4<4;++r4){
        const int row = rA + mi*16 + quad*4 + r4;
        const int col = rB + ni*16 + l15;
        const int g2  = (col>>3) ^ (row&31);   // 32-group XOR swizzle
        sOut[row*256 + g2*8 + (col&7)] = (__bf16)acc[mi][ni][r4];
      }
  asm volatile("" ::: "memory");
  __builtin_amdgcn_s_barrier();
  asm volatile("" ::: "memory");
  #pragma unroll
  for (int it=0; it<16; ++it){
    const int idx = it*512 + tid;
    const int row = idx>>5, gp = idx&31;
    const int gl  = gp ^ (row&31);
    bf16x8 v = *(const bf16x8*)&sOut[row*256 + gp*8];
    const int col0 = n0 + gl*8;
    if (col0 < Nreal){
      const int grow = m0 + row;
      if (col0 < splitN) *(bf16x8*)&C [(size_t)grow*ldc  + col0]          = v;
      else               *(bf16x8*)&C2[(size_t)grow*ldc2 + (col0-splitN)] = v;
    }
  }
}

// ---------------------------------------------------------------------------
// GEMM (B-transposed): bf16 MFMA, 128x128 tile, BK=64, global_load_lds,
// XOR-swizzled LDS, LDS-bounce bf16 epilogue.  Kept for out_proj (N=512:
// 256-tiles would leave half the CUs idle) and the fp32 final head.
// ---------------------------------------------------------------------------
template<typename TC>
__global__ __launch_bounds__(256) void gemm128(
    const __bf16* __restrict__ A, const __bf16* __restrict__ W,
    TC* __restrict__ C, TC* __restrict__ C2, const float* __restrict__ bias,
    int M, int Nreal, int ldc, int ldc2, int splitN, int K, int remapA)
{
  __shared__ __bf16 sAB[2*128*64];     // K-loop: sA | sW ; epilogue: 128x128 tile
  __bf16* sA = sAB;
  __bf16* sW = sAB + 128*64;
  const int tid  = threadIdx.x;
  const int m0   = blockIdx.x*128, n0 = blockIdx.y*128;   // row-tile fastest
  const int lane = tid&63, wave = tid>>6;
  const int l15  = lane&15, quad = lane>>4;
  const int wr   = (wave>>1)*64, wc = (wave&1)*64;
  f32x4 acc[4][4];
  #pragma unroll
  for (int a=0;a<4;++a)
    #pragma unroll
    for (int b=0;b<4;++b) acc[a][b] = (f32x4){0,0,0,0};

  for (int k0=0; k0<K; k0+=64){
    #pragma unroll
    for (int j=0;j<4;++j){
      const int f = j*256 + tid;
      const int r = f>>3;
      const int kc = (((f&7) ^ (r&7)))*8;      // XOR-swizzled source col-block
      int ga = m0 + r;
      if (remapA){ int bb = ga/PREDN; ga = bb*SEQ + (SEQ-PREDN) + (ga - bb*PREDN); }
      gld16(A + (size_t)ga*K + k0 + kc, &sA[f*8]);
      int rb = n0 + r; rb = rb < Nreal ? rb : (Nreal-1);
      gld16(W + (size_t)rb*K + k0 + kc, &sW[f*8]);
    }
    __syncthreads();
    #pragma unroll
    for (int kk=0; kk<64; kk+=32){
      const int kcb = (kk>>3) + quad;          // logical col-block 0..7
      bf16x8 av[4], bv[4];
      #pragma unroll
      for (int mi=0;mi<4;++mi){
        const int row = wr+mi*16+l15;
        av[mi] = *(const bf16x8*)&sA[row*64 + ((kcb ^ (row&7))<<3)];
      }
      #pragma unroll
      for (int ni=0;ni<4;++ni){
        const int row = wc+ni*16+l15;
        bv[ni] = *(const bf16x8*)&sW[row*64 + ((kcb ^ (row&7))<<3)];
      }
      #pragma unroll
      for (int mi=0;mi<4;++mi)
        #pragma unroll
        for (int ni=0;ni<4;++ni)
          acc[mi][ni] = __builtin_amdgcn_mfma_f32_16x16x32_bf16(av[mi],bv[ni],acc[mi][ni],0,0,0);
    }
    __syncthreads();
  }

  if constexpr (sizeof(TC)==2){
    // ---- bf16 epilogue: bounce tile through LDS, coalesced vector stores ----
    #pragma unroll
    for (int mi=0;mi<4;++mi)
      #pragma unroll
      for (int ni=0;ni<4;++ni)
        #pragma unroll
        for (int r4=0;r4<4;++r4){
          const int row = wr+mi*16+quad*4+r4;
          const int col = wc+ni*16+l15;
          const int g2  = (col>>3) ^ (row&15);        // swizzled 8-col group
          sAB[row*128 + g2*8 + (col&7)] = (__bf16)acc[mi][ni][r4];
        }
    __syncthreads();
    #pragma unroll
    for (int it=0; it<8; ++it){
      const int idx = it*256 + tid;
      const int row = idx>>4, g = idx&15;
      const int g2 = g ^ (row&15);
      bf16x8 v = *(const bf16x8*)&sAB[row*128 + g2*8];
      const int col0 = n0 + g*8;
      if (col0 < Nreal){
        const int grow = m0 + row;
        if (col0 < splitN) *(bf16x8*)&C [(size_t)grow*ldc  + col0]          = v;
        else               *(bf16x8*)&C2[(size_t)grow*ldc2 + (col0-splitN)] = v;
      }
    }
  } else {
    // ---- fp32 epilogue (final head): per-element + bias ----
    #pragma unroll
    for (int ni=0;ni<4;++ni){
      const int col = n0 + wc + ni*16 + l15;
      if (col < Nreal){
        const float badd = bias ? bias[col] : 0.f;
        #pragma unroll
        for (int mi=0;mi<4;++mi){
          #pragma unroll
          for (int r4=0;r4<4;++r4){
            const int row = m0 + wr + mi*16 + quad*4 + r4;
            C[(size_t)row*ldc + col] = (TC)(acc[mi][ni][r4] + badd);
          }
        }
      }
    }
  }
}

// ---------------------------------------------------------------------------
// merged fp32->bf16 casts: 4 (src,dst) regions, one launch. n* in float4 units.
// ---------------------------------------------------------------------------
__global__ __launch_bounds__(256) void cast4_k(
    const float* __restrict__ s0, __bf16* __restrict__ d0, int n0,
    const float* __restrict__ s1, __bf16* __restrict__ d1, int n1,
    const float* __restrict__ s2, __bf16* __restrict__ d2, int n2,
    const float* __restrict__ s3, __bf16* __restrict__ d3, int n3)
{
  int i = blockIdx.x*256 + threadIdx.x;
  const float* s; __bf16* d;
  if (i < n0){ s=s0; d=d0; }
  else if ((i-=n0) < n1){ s=s1; d=d1; }
  else if ((i-=n1) < n2){ s=s2; d=d2; }
  else if ((i-=n2) < n3){ s=s3; d=d3; }
  else return;
  float4 v = ((const float4*)s)[i];
  bf16x4 o;
  o[0]=(__bf16)v.x; o[1]=(__bf16)v.y; o[2]=(__bf16)v.z; o[3]=(__bf16)v.w;
  ((bf16x4*)d)[i] = o;
}

// ---------------------------------------------------------------------------
// Causal depthwise conv (width 4) + bias + SiLU, 8 channels per thread.
// ---------------------------------------------------------------------------
__global__ __launch_bounds__(256) void conv_silu_k(
    const __bf16* __restrict__ xbw, const float* __restrict__ cw,
    const float* __restrict__ cb, __bf16* __restrict__ xout,
    __bf16* __restrict__ bcout)
{
  int idx = blockIdx.x*256 + threadIdx.x;
  if (idx >= BATCH*SEQ*CSEG) return;
  const int seg = idx % CSEG;
  const int bt  = idx / CSEG;
  const int t = bt % SEQ, b = bt / SEQ;
  const int d0 = seg*8;
  const __bf16* src = xbw + ((size_t)b*SEQ + t)*XBW + d0;
  bf16x8 z8;
  #pragma unroll
  for (int e=0;e<8;++e) z8[e]=(__bf16)0.f;
  bf16x8 x3 = *(const bf16x8*)src;
  bf16x8 x2 = (t>=1)? *(const bf16x8*)(src -   XBW) : z8;
  bf16x8 x1 = (t>=2)? *(const bf16x8*)(src - 2*XBW) : z8;
  bf16x8 x0 = (t>=3)? *(const bf16x8*)(src - 3*XBW) : z8;
  const float4* w4  = (const float4*)(cw + (size_t)d0*4);
  const float4* cb4 = (const float4*)(cb + d0);
  float4 cbl = cb4[0], cbh = cb4[1];
  bf16x8 o;
  #pragma unroll
  for (int e=0;e<8;++e){
    float4 w = w4[e];
    float acc = (e<4 ? (&cbl.x)[e] : (&cbh.x)[e-4])
              + w.x*(float)x0[e] + w.y*(float)x1[e]
              + w.z*(float)x2[e] + w.w*(float)x3[e];
    o[e] = (__bf16)siluf_(acc);
  }
  if (d0 < DI) *(bf16x8*)(xout  + ((size_t)b*SEQ+t)*DI  + d0)       = o;
  else         *(bf16x8*)(bcout + ((size_t)b*SEQ+t)*128 + (d0-DI))  = o;
}

// ---------------------------------------------------------------------------
// Fused SSD: one block per (b,h). sS aliases sB (dead after mm1; extra
// barrier between mm1 and mask-write) -> LDS 50.2 KB -> 3 blocks/CU.
// ---------------------------------------------------------------------------
__global__ __launch_bounds__(256) void ssd_fused_k(
    const __bf16* __restrict__ bc,
    __bf16* __restrict__ xy,
    const __bf16* __restrict__ xbw,
    const float* __restrict__ dtb_, const float* __restrict__ alog_,
    const float* __restrict__ dp_)
{
  __shared__ __bf16 sPool[5*64*72];
  __bf16* sB   = sPool;                // aliased with sS (sB dead after mm1)
  __bf16* sS   = sPool;
  __bf16* sC   = sPool + 1*64*72;
  __bf16* sXT  = sPool + 2*64*72;
  __bf16* sBwT = sPool + 3*64*72;
  __bf16* sHT  = sPool + 4*64*72;
  __shared__ float sCS[SEQ], sDT[SEQ];
  const int bid = blockIdx.x;
  const int h = bid & 15, b = bid >> 4;
  const int tid = threadIdx.x, wave = tid>>6, lane = tid&63;
  const int l15 = lane&15, quad = lane>>4;
  const int wm = (wave>>1)*32, wn = (wave&1)*32;

  const float Ah  = -__expf(alog_[h]);
  const float dtb = dtb_[h];
  const float Dh  = dp_[h];

  for (int t = tid; t < SEQ; t += 256){
    float raw = (float)xbw[((size_t)b*SEQ + t)*XBW + CDIM + h];
    float dt = softplusf_(raw + dtb);
    sDT[t] = dt;
    sCS[t] = dt*Ah;
  }
  __syncthreads();
  for (int ch = wave; ch < NC; ch += 4){
    float s = sCS[ch*64 + lane];
    #pragma unroll
    for (int off=1; off<64; off<<=1){
      float v = __shfl_up(s, off);
      if (lane >= off) s += v;
    }
    sCS[ch*64 + lane] = s;
  }
  __syncthreads();

  f32x4 run[2][2];
  #pragma unroll
  for (int a=0;a<2;++a)
    #pragma unroll
    for (int d=0;d<2;++d) run[a][d] = (f32x4){0,0,0,0};

  for (int c = 0; c < NC; ++c){
    const int t0 = c*64;
    {
      const int r = tid>>2, seg = (tid&3)*16;
      const __bf16* row = bc + ((size_t)b*SEQ + t0 + r)*128;
      bf16x8 vb0 = *(const bf16x8*)(row + seg);
      bf16x8 vb1 = *(const bf16x8*)(row + seg + 8);
      bf16x8 vc0 = *(const bf16x8*)(row + 64 + seg);
      bf16x8 vc1 = *(const bf16x8*)(row + 64 + seg + 8);
      *(bf16x8*)&sB[r*72+seg]   = vb0;
      *(bf16x8*)&sB[r*72+seg+8] = vb1;
      *(bf16x8*)&sC[r*72+seg]   = vc0;
      *(bf16x8*)&sC[r*72+seg+8] = vc1;
      const float w = __expf(sCS[t0+63] - sCS[t0+r]) * sDT[t0+r];  // <=0 exp
      #pragma unroll
      for (int e=0;e<8;++e){
        sBwT[(seg+e)*72 + r]   = (__bf16)(w*(float)vb0[e]);
        sBwT[(seg+8+e)*72 + r] = (__bf16)(w*(float)vb1[e]);
      }
      const __bf16* xrow = xy + ((size_t)b*SEQ + t0 + r)*DI + h*64;
      bf16x8 vx0 = *(const bf16x8*)(xrow + seg);
      bf16x8 vx1 = *(const bf16x8*)(xrow + seg + 8);
      #pragma unroll
      for (int e=0;e<8;++e){
        sXT[(seg+e)*72 + r]   = vx0[e];
        sXT[(seg+8+e)*72 + r] = vx1[e];
      }
    }
    __syncthreads();

    f32x4 aS[2][2];
    #pragma unroll
    for (int a=0;a<2;++a)
      #pragma unroll
      for (int d=0;d<2;++d) aS[a][d] = (f32x4){0,0,0,0};
    #pragma unroll
    for (int kk=0; kk<64; kk+=32){
      const int kf = kk + quad*8;
      bf16x8 a0 = *(const bf16x8*)&sC[(wm+l15)*72+kf];
      bf16x8 a1 = *(const bf16x8*)&sC[(wm+16+l15)*72+kf];
      bf16x8 b0 = *(const bf16x8*)&sB[(wn+l15)*72+kf];
      bf16x8 b1 = *(const bf16x8*)&sB[(wn+16+l15)*72+kf];
      aS[0][0] = __builtin_amdgcn_mfma_f32_16x16x32_bf16(a0,b0,aS[0][0],0,0,0);
      aS[0][1] = __builtin_amdgcn_mfma_f32_16x16x32_bf16(a0,b1,aS[0][1],0,0,0);
      aS[1][0] = __builtin_amdgcn_mfma_f32_16x16x32_bf16(a1,b0,aS[1][0],0,0,0);
      aS[1][1] = __builtin_amdgcn_mfma_f32_16x16x32_bf16(a1,b1,aS[1][1],0,0,0);
    }
    __syncthreads();   // all waves done reading sB before sS(=sB) is written

    #pragma unroll
    for (int mi=0;mi<2;++mi)
      #pragma unroll
      for (int ni=0;ni<2;++ni)
        #pragma unroll
        for (int r4=0;r4<4;++r4){
          const int i = wm+mi*16+quad*4+r4, j = wn+ni*16+l15;
          float ed = __expf(fminf(sCS[t0+i]-sCS[t0+j], 0.f)) * sDT[t0+j];
          float v = aS[mi][ni][r4]*ed;
          sS[i*72+j] = (__bf16)((j<=i)? v : 0.f);
          sHT[j*72+i] = (__bf16)run[mi][ni][r4];   // [p][n]
        }
    __syncthreads();

    f32x4 aY[2][2], aH[2][2], aYi[2][2];
    #pragma unroll
    for (int a=0;a<2;++a)
      #pragma unroll
      for (int d=0;d<2;++d){
        aY[a][d]=(f32x4){0,0,0,0}; aH[a][d]=(f32x4){0,0,0,0};
        aYi[a][d]=(f32x4){0,0,0,0};
      }
    #pragma unroll
    for (int kk=0; kk<64; kk+=32){
      const int kf = kk + quad*8;
      bf16x8 b0 = *(const bf16x8*)&sXT[(wn+l15)*72+kf];
      bf16x8 b1 = *(const bf16x8*)&sXT[(wn+16+l15)*72+kf];
      bf16x8 s0 = *(const bf16x8*)&sS[(wm+l15)*72+kf];
      bf16x8 s1 = *(const bf16x8*)&sS[(wm+16+l15)*72+kf];
      bf16x8 w0 = *(const bf16x8*)&sBwT[(wm+l15)*72+kf];
      bf16x8 w1 = *(const bf16x8*)&sBwT[(wm+16+l15)*72+kf];
      bf16x8 c0 = *(const bf16x8*)&sC[(wm+l15)*72+kf];
      bf16x8 c1 = *(const bf16x8*)&sC[(wm+16+l15)*72+kf];
      bf16x8 h0 = *(const bf16x8*)&sHT[(wn+l15)*72+kf];
      bf16x8 h1 = *(const bf16x8*)&sHT[(wn+16+l15)*72+kf];
      aY[0][0] = __builtin_amdgcn_mfma_f32_16x16x32_bf16(s0,b0,aY[0][0],0,0,0);
      aY[0][1] = __builtin_amdgcn_mfma_f32_16x16x32_bf16(s0,b1,aY[0][1],0,0,0);
      aY[1][0] = __builtin_amdgcn_mfma_f32_16x16x32_bf16(s1,b0,aY[1][0],0,0,0);
      aY[1][1] = __builtin_amdgcn_mfma_f32_16x16x32_bf16(s1,b1,aY[1][1],0,0,0);
      aH[0][0] = __builtin_amdgcn_mfma_f32_16x16x32_bf16(w0,b0,aH[0][0],0,0,0);
      aH[0][1] = __builtin_amdgcn_mfma_f32_16x16x32_bf16(w0,b1,aH[0][1],0,0,0);
      aH[1][0] = __builtin_amdgcn_mfma_f32_16x16x32_bf16(w1,b0,aH[1][0],0,0,0);
      aH[1][1] = __builtin_amdgcn_mfma_f32_16x16x32_bf16(w1,b1,aH[1][1],0,0,0);
      aYi[0][0] = __builtin_amdgcn_mfma_f32_16x16x32_bf16(c0,h0,aYi[0][0],0,0,0);
      aYi[0][1] = __builtin_amdgcn_mfma_f32_16x16x32_bf16(c0,h1,aYi[0][1],0,0,0);
      aYi[1][0] = __builtin_amdgcn_mfma_f32_16x16x32_bf16(c1,h0,aYi[1][0],0,0,0);
      aYi[1][1] = __builtin_amdgcn_mfma_f32_16x16x32_bf16(c1,h1,aYi[1][1],0,0,0);
    }

    const float lam = __expf(sCS[t0+63]);
    #pragma unroll
    for (int mi=0;mi<2;++mi)
      #pragma unroll
      for (int ni=0;ni<2;++ni)
        #pragma unroll
        for (int r4=0;r4<4;++r4){
          const int i = wm+mi*16+quad*4+r4;
          const int p = wn+ni*16+l15;
          const float xval = (float)sXT[p*72 + i];
          const float e2 = __expf(sCS[t0+i]);    // <=1 (cs<=0)
          const float yv = aY[mi][ni][r4] + Dh*xval + e2*aYi[mi][ni][r4];
          xy[((size_t)b*SEQ + t0 + i)*DI + h*64 + p] = (__bf16)yv;
          run[mi][ni][r4] = run[mi][ni][r4]*lam + aH[mi][ni][r4];
        }
    __syncthreads();
  }
}

// ---------------------------------------------------------------------------
__global__ __launch_bounds__(256) void gate_rms_k(
    __bf16* __restrict__ y, const __bf16* __restrict__ z, const float* __restrict__ nw)
{
  __shared__ float red[4];
  const int tid = threadIdx.x;
  const int sub = tid>>7;
  const int off = (tid&127)*8;
  const size_t row = (size_t)blockIdx.x*2 + sub;
  __bf16* yrow = y + row*DI;
  const __bf16* zrow = z + row*DI;
  bf16x8 yv = *(const bf16x8*)(yrow+off);
  bf16x8 zv = *(const bf16x8*)(zrow+off);
  float u[8]; float ss = 0.f;
  #pragma unroll
  for (int e=0;e<8;++e){
    float uu = (float)yv[e]*siluf_((float)zv[e]);
    u[e]=uu; ss += uu*uu;
  }
  #pragma unroll
  for (int o=32;o;o>>=1) ss += __shfl_xor(ss,o);
  if ((tid&63)==0) red[tid>>6] = ss;
  __syncthreads();
  ss = red[sub*2] + red[sub*2+1];
  const float sc = rsqrtf(ss*(1.f/DI) + EPSF);
  const float4* nw4 = (const float4*)(nw + off);
  float4 n0 = nw4[0], n1 = nw4[1];
  bf16x8 o;
  #pragma unroll
  for (int e=0;e<8;++e)
    o[e] = (__bf16)(u[e]*sc*(e<4 ? (&n0.x)[e] : (&n1.x)[e-4]));
  *(bf16x8*)(yrow+off) = o;
}

// ---------------------------------------------------------------------------
__global__ __launch_bounds__(256) void add_ln_k(
    const __bf16* __restrict__ tmp, __bf16* __restrict__ resio,
    const float* __restrict__ w, const float* __restrict__ bb)
{
  const int tid = threadIdx.x, lane = tid&63;
  const size_t row = (size_t)blockIdx.x*4 + (tid>>6);
  const int off = lane*8;
  const __bf16* trow = tmp + row*DM;
  __bf16* rrow = resio + row*DM;
  bf16x8 tv = *(const bf16x8*)(trow+off);
  bf16x8 rv = *(const bf16x8*)(rrow+off);
  float v[8]; float s = 0.f;
  #pragma unroll
  for (int e=0;e<8;++e){ v[e]=(float)tv[e]+(float)rv[e]; s += v[e]; }
  #pragma unroll
  for (int o=32;o;o>>=1) s += __shfl_xor(s,o);
  const float mean = s*(1.f/DM);
  float q = 0.f;
  #pragma unroll
  for (int e=0;e<8;++e){ v[e]-=mean; q += v[e]*v[e]; }
  #pragma unroll
  for (int o=32;o;o>>=1) q += __shfl_xor(q,o);
  const float rstd = rsqrtf(q*(1.f/DM) + EPSF);
  const float4* w4 = (const float4*)(w + off);
  const float4* b4 = (const float4*)(bb + off);
  float4 w0=w4[0], w1=w4[1], b0=b4[0], b1=b4[1];
  bf16x8 o8;
  #pragma unroll
  for (int e=0;e<8;++e){
    float we = e<4 ? (&w0.x)[e] : (&w1.x)[e-4];
    float be = e<4 ? (&b0.x)[e] : (&b1.x)[e-4];
    o8[e] = (__bf16)(v[e]*rstd*we + be);
  }
  *(bf16x8*)(rrow+off) = o8;
}

// ---------------------------------------------------------------------------
extern "C" void kernel_launch(void* const* d_in, const int* in_sizes, int n_in,
                              void* d_out, int out_size, void* d_ws, size_t ws_size,
                              hipStream_t stream)
{
  const float* x         = (const float*)d_in[0];
  const float* in_proj_w = (const float*)d_in[1];
  const float* conv_w    = (const float*)d_in[2];
  const float* conv_b    = (const float*)d_in[3];
  const float* dt_bias   = (const float*)d_in[4];
  const float* A_log     = (const float*)d_in[5];
  const float* Dp        = (const float*)d_in[6];
  const float* norm_w    = (const float*)d_in[7];
  const float* out_proj_w= (const float*)d_in[8];
  const float* ln_w      = (const float*)d_in[9];
  const float* ln_b      = (const float*)d_in[10];
  const float* final_w   = (const float*)d_in[11];
  const float* final_b   = (const float*)d_in[12];
  float* out = (float*)d_out;

  const size_t ROWS = (size_t)BATCH*SEQ;        // 16384
  __bf16* wbf_in  = (__bf16*)d_ws;
  __bf16* wbf_out = wbf_in  + (size_t)NL*DPROJ*DM;
  __bf16* wbf_fin = wbf_out + (size_t)NL*DM*DI;
  __bf16* zbuf    = wbf_fin + (size_t)DM*DM;
  __bf16* xbw     = zbuf    + ROWS*DI;
  __bf16* ybuf    = xbw     + ROWS*XBW;
  __bf16* bcb     = ybuf    + ROWS*DI;
  __bf16* xcur    = bcb     + ROWS*128;
  __bf16* tmp  = xbw;     // alias: xbw dead after ssd_fused reads dt

  {
    int n1 = NL*DPROJ*DM/4, n2 = NL*DM*DI/4, n3 = DM*DM/4, n4 = (int)(ROWS*DM/4);
    int tot = n1+n2+n3+n4;
    cast4_k<<<(tot+255)/256, 256, 0, stream>>>(
        in_proj_w, wbf_in, n1, out_proj_w, wbf_out, n2,
        final_w, wbf_fin, n3, x, xcur, n4);
  }

  const int convTotal = BATCH*SEQ*CSEG;
  const int BIGN = 1<<30;

  for (int l=0; l<NL; ++l){
    const __bf16* wl = wbf_in + (size_t)l*DPROJ*DM;
    // in_proj: 256x256 2-phase pipelined GEMM (grid x = row-tile, XCD locality)
    gemm256<<<dim3((int)(ROWS/256), (DPROJ+255)/256), 512, 0, stream>>>(
        xcur, wl, zbuf, xbw, DPROJ, DI, XBW, DI, DM);
    conv_silu_k<<<(convTotal+255)/256, 256, 0, stream>>>(
        xbw, conv_w + (size_t)l*CDIM*4, conv_b + (size_t)l*CDIM, ybuf, bcb);
    ssd_fused_k<<<BATCH*NH, 256, 0, stream>>>(
        bcb, ybuf, xbw, dt_bias + l*NH, A_log + l*NH, Dp + l*NH);
    gate_rms_k<<<(int)(ROWS/2), 256, 0, stream>>>(ybuf, zbuf, norm_w + (size_t)l*DI);
    gemm128<__bf16><<<dim3((int)(ROWS/128), DM/128), 256, 0, stream>>>(
        ybuf, wbf_out + (size_t)l*DM*DI, tmp, tmp, nullptr, (int)ROWS, DM, DM, DM, BIGN, DI, 0);
    add_ln_k<<<(int)(ROWS/4), 256, 0, stream>>>(tmp, xcur, ln_w + l*DM, ln_b + l*DM);
  }
  // final head: A-rows remapped to the last PREDN timesteps of xcur
  gemm128<float><<<dim3((BATCH*PREDN)/128, DM/128), 256, 0, stream>>>(
      xcur, wbf_fin, out, out, final_b, BATCH*PREDN, DM, DM, DM, BIGN, DM, 1);
}

// Round 4
// 859.007 us; speedup vs baseline: 1.0601x; 1.0410x over previous
//
#include <hip/hip_runtime.h>
#include <stdint.h>

#define BATCH 32
#define SEQ   512
#define DM    512
#define NL    4
#define DSTATE 64
#define DI    1024   // D_INNER
#define NH    16
#define HD    64
#define PREDN 96
#define CDIM  1152   // DI + 2*DSTATE
#define CSEG  144    // CDIM/8
#define DPROJ 2192
#define XBW   1168   // xBC (1152) + dt (16) columns
#define NC    8      // chunks per sequence
#define EPSF  1e-5f

typedef float  f32x4  __attribute__((ext_vector_type(4)));
typedef __bf16 bf16x4 __attribute__((ext_vector_type(4)));
typedef __bf16 bf16x8 __attribute__((ext_vector_type(8)));

__device__ __forceinline__ float sigmoidf_(float x){ return 1.f/(1.f+__expf(-x)); }
__device__ __forceinline__ float siluf_(float x){ return x*sigmoidf_(x); }
__device__ __forceinline__ float softplusf_(float x){ return (x>20.f)?x:log1pf(__expf(x)); }

// direct global->LDS async copy, 16B per lane
__device__ __forceinline__ void gld16(const void* g, void* l){
  __builtin_amdgcn_global_load_lds((__attribute__((address_space(1))) void*)g,
                                   (__attribute__((address_space(3))) void*)l, 16, 0, 0);
}

// ---------------------------------------------------------------------------
// GEMM (B-transposed): bf16 MFMA, 128x128 tile, BK=64, global_load_lds,
// XOR-swizzled LDS, LDS-bounce bf16 epilogue.  R11: back as the in_proj
// kernel (R9/R10 256-tile pipelines capped at ~23% MfmaUtil on this shape:
// K=512 too short + 1 block/CU lockstep; gemm128 gets overlap from 3+
// resident blocks -> 643 TF, 57 us).
// ---------------------------------------------------------------------------
template<typename TC>
__global__ __launch_bounds__(256) void gemm128(
    const __bf16* __restrict__ A, const __bf16* __restrict__ W,
    TC* __restrict__ C, TC* __restrict__ C2, const float* __restrict__ bias,
    int M, int Nreal, int ldc, int ldc2, int splitN, int K, int remapA)
{
  __shared__ __bf16 sAB[2*128*64];     // K-loop: sA | sW ; epilogue: 128x128 tile
  __bf16* sA = sAB;
  __bf16* sW = sAB + 128*64;
  const int tid  = threadIdx.x;
  const int m0   = blockIdx.x*128, n0 = blockIdx.y*128;   // row-tile fastest
  const int lane = tid&63, wave = tid>>6;
  const int l15  = lane&15, quad = lane>>4;
  const int wr   = (wave>>1)*64, wc = (wave&1)*64;
  f32x4 acc[4][4];
  #pragma unroll
  for (int a=0;a<4;++a)
    #pragma unroll
    for (int b=0;b<4;++b) acc[a][b] = (f32x4){0,0,0,0};

  for (int k0=0; k0<K; k0+=64){
    #pragma unroll
    for (int j=0;j<4;++j){
      const int f = j*256 + tid;
      const int r = f>>3;
      const int kc = (((f&7) ^ (r&7)))*8;      // XOR-swizzled source col-block
      int ga = m0 + r;
      if (remapA){ int bb = ga/PREDN; ga = bb*SEQ + (SEQ-PREDN) + (ga - bb*PREDN); }
      gld16(A + (size_t)ga*K + k0 + kc, &sA[f*8]);
      int rb = n0 + r; rb = rb < Nreal ? rb : (Nreal-1);
      gld16(W + (size_t)rb*K + k0 + kc, &sW[f*8]);
    }
    __syncthreads();
    #pragma unroll
    for (int kk=0; kk<64; kk+=32){
      const int kcb = (kk>>3) + quad;          // logical col-block 0..7
      bf16x8 av[4], bv[4];
      #pragma unroll
      for (int mi=0;mi<4;++mi){
        const int row = wr+mi*16+l15;
        av[mi] = *(const bf16x8*)&sA[row*64 + ((kcb ^ (row&7))<<3)];
      }
      #pragma unroll
      for (int ni=0;ni<4;++ni){
        const int row = wc+ni*16+l15;
        bv[ni] = *(const bf16x8*)&sW[row*64 + ((kcb ^ (row&7))<<3)];
      }
      #pragma unroll
      for (int mi=0;mi<4;++mi)
        #pragma unroll
        for (int ni=0;ni<4;++ni)
          acc[mi][ni] = __builtin_amdgcn_mfma_f32_16x16x32_bf16(av[mi],bv[ni],acc[mi][ni],0,0,0);
    }
    __syncthreads();
  }

  if constexpr (sizeof(TC)==2){
    // ---- bf16 epilogue: bounce tile through LDS, coalesced vector stores ----
    #pragma unroll
    for (int mi=0;mi<4;++mi)
      #pragma unroll
      for (int ni=0;ni<4;++ni)
        #pragma unroll
        for (int r4=0;r4<4;++r4){
          const int row = wr+mi*16+quad*4+r4;
          const int col = wc+ni*16+l15;
          const int g2  = (col>>3) ^ (row&15);        // swizzled 8-col group
          sAB[row*128 + g2*8 + (col&7)] = (__bf16)acc[mi][ni][r4];
        }
    __syncthreads();
    #pragma unroll
    for (int it=0; it<8; ++it){
      const int idx = it*256 + tid;
      const int row = idx>>4, g = idx&15;
      const int g2 = g ^ (row&15);
      bf16x8 v = *(const bf16x8*)&sAB[row*128 + g2*8];
      const int col0 = n0 + g*8;
      if (col0 < Nreal){
        const int grow = m0 + row;
        if (col0 < splitN) *(bf16x8*)&C [(size_t)grow*ldc  + col0]          = v;
        else               *(bf16x8*)&C2[(size_t)grow*ldc2 + (col0-splitN)] = v;
      }
    }
  } else {
    // ---- fp32 epilogue (final head): per-element + bias ----
    #pragma unroll
    for (int ni=0;ni<4;++ni){
      const int col = n0 + wc + ni*16 + l15;
      if (col < Nreal){
        const float badd = bias ? bias[col] : 0.f;
        #pragma unroll
        for (int mi=0;mi<4;++mi){
          #pragma unroll
          for (int r4=0;r4<4;++r4){
            const int row = m0 + wr + mi*16 + quad*4 + r4;
            C[(size_t)row*ldc + col] = (TC)(acc[mi][ni][r4] + badd);
          }
        }
      }
    }
  }
}

// ---------------------------------------------------------------------------
// R11 NEW: fused out_proj GEMM (+residual +LayerNorm) -> xcur in-place.
// Tile 64x512 (BN = full N) so every output row is block-local -> LN in the
// epilogue via per-wave partial sums + 2KB LDS cross-wave reduce.  Kills the
// tmp round-trip (48 MB/layer) and the add_ln launch.
// 512 thr = 8 waves (2m x 4n), each wave 32x128.  BK=64, double-buffered
// LDS (2 x 72 KB), stage(t+1) issued BEFORE compute(t), single
// vmcnt(0)+barrier per K-step -> staging overlaps MFMA.  Grid = 256 = 1/CU,
// no tail.  Same XOR source-swizzle as gemm128 (bank-conflict-free).
// ---------------------------------------------------------------------------
__global__ __launch_bounds__(512) void gemm_ln_k(
    const __bf16* __restrict__ A,   // ybuf  [ROWS][1024]
    const __bf16* __restrict__ W,   // wbf_out [512][1024]
    __bf16* __restrict__ R,         // xcur  [ROWS][512]  (residual in / out)
    const float* __restrict__ lw, const float* __restrict__ lb)
{
  __shared__ __bf16 sm[2][(64+512)*64];   // [buf][ A 64x64 | B 512x64 ]
  __shared__ float sLN[4][64][2];         // [wn][local row][sum,sumsq]
  const int tid  = threadIdx.x;
  const int m0   = blockIdx.x*64;
  const int lane = tid&63;
  const int wave = tid>>6;
  const int l15  = lane&15, quad = lane>>4;
  const int wm   = wave>>2, wn = wave&3;   // 2 x 4 wave grid
  const int nt   = DI/64;                  // 16

  f32x4 acc[2][8];
  #pragma unroll
  for (int a=0;a<2;++a)
    #pragma unroll
    for (int b=0;b<8;++b) acc[a][b] = (f32x4){0,0,0,0};

  auto stage = [&](int bsel, int kt){
    __bf16* dA = &sm[bsel][0];
    __bf16* dB = &sm[bsel][64*64];
    const int k0 = kt*64;
    {    // A: 8 KB -> 1 gld16 / thread
      const int rl = tid>>3, pb = tid&7;
      const int kc = (pb ^ (rl&7))<<3;
      gld16(A + (size_t)(m0+rl)*DI + k0 + kc, dA + rl*64 + pb*8);
    }
    #pragma unroll
    for (int j=0;j<8;++j){  // B: 64 KB -> 8 gld16 / thread
      const int s  = j*512 + tid;
      const int rl = s>>3, pb = s&7;
      const int kc = (pb ^ (rl&7))<<3;
      gld16(W + (size_t)rl*DI + k0 + kc, dB + rl*64 + pb*8);
    }
  };

  stage(0, 0);
  asm volatile("s_waitcnt vmcnt(0)" ::: "memory");
  __builtin_amdgcn_s_barrier();
  asm volatile("" ::: "memory");

  for (int t=0; t<nt; ++t){
    const int ct = t&1;
    if (t+1<nt) stage(ct^1, t+1);
    asm volatile("" ::: "memory");
    const __bf16* bA = &sm[ct][0];
    const __bf16* bB = &sm[ct][64*64];
    #pragma unroll
    for (int kk=0; kk<2; ++kk){
      const int kcb = kk*4 + quad;
      bf16x8 av[2], bv[8];
      #pragma unroll
      for (int mi=0;mi<2;++mi){
        const int row = wm*32 + mi*16 + l15;
        av[mi] = *(const bf16x8*)&bA[row*64 + ((kcb ^ (row&7))<<3)];
      }
      #pragma unroll
      for (int ni=0;ni<8;++ni){
        const int row = wn*128 + ni*16 + l15;
        bv[ni] = *(const bf16x8*)&bB[row*64 + ((kcb ^ (row&7))<<3)];
      }
      #pragma unroll
      for (int mi=0;mi<2;++mi)
        #pragma unroll
        for (int ni=0;ni<8;++ni)
          acc[mi][ni] = __builtin_amdgcn_mfma_f32_16x16x32_bf16(av[mi],bv[ni],acc[mi][ni],0,0,0);
    }
    if (t+1<nt) asm volatile("s_waitcnt vmcnt(0)" ::: "memory");  // next tile landed
    asm volatile("" ::: "memory");
    __builtin_amdgcn_s_barrier();   // all waves done with buf ct; next tile ready
    asm volatile("" ::: "memory");
  }

  // ---- epilogue: +residual, LN over each full row (block-local) ----
  // hoisted LN params (cols depend only on ni)
  float lwv[8], lbv[8];
  #pragma unroll
  for (int ni=0;ni<8;++ni){
    const int col = wn*128 + ni*16 + l15;
    lwv[ni] = lw[col]; lbv[ni] = lb[col];
  }
  #pragma unroll
  for (int mi=0;mi<2;++mi)
    #pragma unroll
    for (int r4=0;r4<4;++r4){
      const int lr = wm*32 + mi*16 + quad*4 + r4;
      const size_t rg = (size_t)(m0 + lr)*DM;
      float s = 0.f, q = 0.f;
      #pragma unroll
      for (int ni=0;ni<8;++ni){
        const int col = wn*128 + ni*16 + l15;
        float v = acc[mi][ni][r4] + (float)R[rg + col];
        acc[mi][ni][r4] = v;
        s += v; q += v*v;
      }
      #pragma unroll
      for (int o=1;o<16;o<<=1){ s += __shfl_xor(s,o); q += __shfl_xor(q,o); }
      if (l15==0){ sLN[wn][lr][0] = s; sLN[wn][lr][1] = q; }
    }
  __syncthreads();
  #pragma unroll
  for (int mi=0;mi<2;++mi)
    #pragma unroll
    for (int r4=0;r4<4;++r4){
      const int lr = wm*32 + mi*16 + quad*4 + r4;
      const float S = sLN[0][lr][0]+sLN[1][lr][0]+sLN[2][lr][0]+sLN[3][lr][0];
      const float Q = sLN[0][lr][1]+sLN[1][lr][1]+sLN[2][lr][1]+sLN[3][lr][1];
      const float mean = S*(1.f/DM);
      const float rstd = rsqrtf(fmaxf(Q*(1.f/DM) - mean*mean, 0.f) + EPSF);
      const size_t rg = (size_t)(m0 + lr)*DM;
      #pragma unroll
      for (int ni=0;ni<8;++ni){
        const int col = wn*128 + ni*16 + l15;
        R[rg + col] = (__bf16)((acc[mi][ni][r4] - mean)*rstd*lwv[ni] + lbv[ni]);
      }
    }
}

// ---------------------------------------------------------------------------
// merged fp32->bf16 casts: 4 (src,dst) regions, one launch. n* in float4 units.
// ---------------------------------------------------------------------------
__global__ __launch_bounds__(256) void cast4_k(
    const float* __restrict__ s0, __bf16* __restrict__ d0, int n0,
    const float* __restrict__ s1, __bf16* __restrict__ d1, int n1,
    const float* __restrict__ s2, __bf16* __restrict__ d2, int n2,
    const float* __restrict__ s3, __bf16* __restrict__ d3, int n3)
{
  int i = blockIdx.x*256 + threadIdx.x;
  const float* s; __bf16* d;
  if (i < n0){ s=s0; d=d0; }
  else if ((i-=n0) < n1){ s=s1; d=d1; }
  else if ((i-=n1) < n2){ s=s2; d=d2; }
  else if ((i-=n2) < n3){ s=s3; d=d3; }
  else return;
  float4 v = ((const float4*)s)[i];
  bf16x4 o;
  o[0]=(__bf16)v.x; o[1]=(__bf16)v.y; o[2]=(__bf16)v.z; o[3]=(__bf16)v.w;
  ((bf16x4*)d)[i] = o;
}

// ---------------------------------------------------------------------------
// Causal depthwise conv (width 4) + bias + SiLU, 8 channels per thread.
// ---------------------------------------------------------------------------
__global__ __launch_bounds__(256) void conv_silu_k(
    const __bf16* __restrict__ xbw, const float* __restrict__ cw,
    const float* __restrict__ cb, __bf16* __restrict__ xout,
    __bf16* __restrict__ bcout)
{
  int idx = blockIdx.x*256 + threadIdx.x;
  if (idx >= BATCH*SEQ*CSEG) return;
  const int seg = idx % CSEG;
  const int bt  = idx / CSEG;
  const int t = bt % SEQ, b = bt / SEQ;
  const int d0 = seg*8;
  const __bf16* src = xbw + ((size_t)b*SEQ + t)*XBW + d0;
  bf16x8 z8;
  #pragma unroll
  for (int e=0;e<8;++e) z8[e]=(__bf16)0.f;
  bf16x8 x3 = *(const bf16x8*)src;
  bf16x8 x2 = (t>=1)? *(const bf16x8*)(src -   XBW) : z8;
  bf16x8 x1 = (t>=2)? *(const bf16x8*)(src - 2*XBW) : z8;
  bf16x8 x0 = (t>=3)? *(const bf16x8*)(src - 3*XBW) : z8;
  const float4* w4  = (const float4*)(cw + (size_t)d0*4);
  const float4* cb4 = (const float4*)(cb + d0);
  float4 cbl = cb4[0], cbh = cb4[1];
  bf16x8 o;
  #pragma unroll
  for (int e=0;e<8;++e){
    float4 w = w4[e];
    float acc = (e<4 ? (&cbl.x)[e] : (&cbh.x)[e-4])
              + w.x*(float)x0[e] + w.y*(float)x1[e]
              + w.z*(float)x2[e] + w.w*(float)x3[e];
    o[e] = (__bf16)siluf_(acc);
  }
  if (d0 < DI) *(bf16x8*)(xout  + ((size_t)b*SEQ+t)*DI  + d0)       = o;
  else         *(bf16x8*)(bcout + ((size_t)b*SEQ+t)*128 + (d0-DI))  = o;
}

// ---------------------------------------------------------------------------
// Fused SSD: one block per (b,h). sS aliases sB (dead after mm1; extra
// barrier between mm1 and mask-write) -> LDS 50.2 KB -> 3 blocks/CU.
// ---------------------------------------------------------------------------
__global__ __launch_bounds__(256) void ssd_fused_k(
    const __bf16* __restrict__ bc,
    __bf16* __restrict__ xy,
    const __bf16* __restrict__ xbw,
    const float* __restrict__ dtb_, const float* __restrict__ alog_,
    const float* __restrict__ dp_)
{
  __shared__ __bf16 sPool[5*64*72];
  __bf16* sB   = sPool;                // aliased with sS (sB dead after mm1)
  __bf16* sS   = sPool;
  __bf16* sC   = sPool + 1*64*72;
  __bf16* sXT  = sPool + 2*64*72;
  __bf16* sBwT = sPool + 3*64*72;
  __bf16* sHT  = sPool + 4*64*72;
  __shared__ float sCS[SEQ], sDT[SEQ];
  const int bid = blockIdx.x;
  const int h = bid & 15, b = bid >> 4;
  const int tid = threadIdx.x, wave = tid>>6, lane = tid&63;
  const int l15 = lane&15, quad = lane>>4;
  const int wm = (wave>>1)*32, wn = (wave&1)*32;

  const float Ah  = -__expf(alog_[h]);
  const float dtb = dtb_[h];
  const float Dh  = dp_[h];

  for (int t = tid; t < SEQ; t += 256){
    float raw = (float)xbw[((size_t)b*SEQ + t)*XBW + CDIM + h];
    float dt = softplusf_(raw + dtb);
    sDT[t] = dt;
    sCS[t] = dt*Ah;
  }
  __syncthreads();
  for (int ch = wave; ch < NC; ch += 4){
    float s = sCS[ch*64 + lane];
    #pragma unroll
    for (int off=1; off<64; off<<=1){
      float v = __shfl_up(s, off);
      if (lane >= off) s += v;
    }
    sCS[ch*64 + lane] = s;
  }
  __syncthreads();

  f32x4 run[2][2];
  #pragma unroll
  for (int a=0;a<2;++a)
    #pragma unroll
    for (int d=0;d<2;++d) run[a][d] = (f32x4){0,0,0,0};

  for (int c = 0; c < NC; ++c){
    const int t0 = c*64;
    {
      const int r = tid>>2, seg = (tid&3)*16;
      const __bf16* row = bc + ((size_t)b*SEQ + t0 + r)*128;
      bf16x8 vb0 = *(const bf16x8*)(row + seg);
      bf16x8 vb1 = *(const bf16x8*)(row + seg + 8);
      bf16x8 vc0 = *(const bf16x8*)(row + 64 + seg);
      bf16x8 vc1 = *(const bf16x8*)(row + 64 + seg + 8);
      *(bf16x8*)&sB[r*72+seg]   = vb0;
      *(bf16x8*)&sB[r*72+seg+8] = vb1;
      *(bf16x8*)&sC[r*72+seg]   = vc0;
      *(bf16x8*)&sC[r*72+seg+8] = vc1;
      const float w = __expf(sCS[t0+63] - sCS[t0+r]) * sDT[t0+r];  // <=0 exp
      #pragma unroll
      for (int e=0;e<8;++e){
        sBwT[(seg+e)*72 + r]   = (__bf16)(w*(float)vb0[e]);
        sBwT[(seg+8+e)*72 + r] = (__bf16)(w*(float)vb1[e]);
      }
      const __bf16* xrow = xy + ((size_t)b*SEQ + t0 + r)*DI + h*64;
      bf16x8 vx0 = *(const bf16x8*)(xrow + seg);
      bf16x8 vx1 = *(const bf16x8*)(xrow + seg + 8);
      #pragma unroll
      for (int e=0;e<8;++e){
        sXT[(seg+e)*72 + r]   = vx0[e];
        sXT[(seg+8+e)*72 + r] = vx1[e];
      }
    }
    __syncthreads();

    f32x4 aS[2][2];
    #pragma unroll
    for (int a=0;a<2;++a)
      #pragma unroll
      for (int d=0;d<2;++d) aS[a][d] = (f32x4){0,0,0,0};
    #pragma unroll
    for (int kk=0; kk<64; kk+=32){
      const int kf = kk + quad*8;
      bf16x8 a0 = *(const bf16x8*)&sC[(wm+l15)*72+kf];
      bf16x8 a1 = *(const bf16x8*)&sC[(wm+16+l15)*72+kf];
      bf16x8 b0 = *(const bf16x8*)&sB[(wn+l15)*72+kf];
      bf16x8 b1 = *(const bf16x8*)&sB[(wn+16+l15)*72+kf];
      aS[0][0] = __builtin_amdgcn_mfma_f32_16x16x32_bf16(a0,b0,aS[0][0],0,0,0);
      aS[0][1] = __builtin_amdgcn_mfma_f32_16x16x32_bf16(a0,b1,aS[0][1],0,0,0);
      aS[1][0] = __builtin_amdgcn_mfma_f32_16x16x32_bf16(a1,b0,aS[1][0],0,0,0);
      aS[1][1] = __builtin_amdgcn_mfma_f32_16x16x32_bf16(a1,b1,aS[1][1],0,0,0);
    }
    __syncthreads();   // all waves done reading sB before sS(=sB) is written

    #pragma unroll
    for (int mi=0;mi<2;++mi)
      #pragma unroll
      for (int ni=0;ni<2;++ni)
        #pragma unroll
        for (int r4=0;r4<4;++r4){
          const int i = wm+mi*16+quad*4+r4, j = wn+ni*16+l15;
          float ed = __expf(fminf(sCS[t0+i]-sCS[t0+j], 0.f)) * sDT[t0+j];
          float v = aS[mi][ni][r4]*ed;
          sS[i*72+j] = (__bf16)((j<=i)? v : 0.f);
          sHT[j*72+i] = (__bf16)run[mi][ni][r4];   // [p][n]
        }
    __syncthreads();

    f32x4 aY[2][2], aH[2][2], aYi[2][2];
    #pragma unroll
    for (int a=0;a<2;++a)
      #pragma unroll
      for (int d=0;d<2;++d){
        aY[a][d]=(f32x4){0,0,0,0}; aH[a][d]=(f32x4){0,0,0,0};
        aYi[a][d]=(f32x4){0,0,0,0};
      }
    #pragma unroll
    for (int kk=0; kk<64; kk+=32){
      const int kf = kk + quad*8;
      bf16x8 b0 = *(const bf16x8*)&sXT[(wn+l15)*72+kf];
      bf16x8 b1 = *(const bf16x8*)&sXT[(wn+16+l15)*72+kf];
      bf16x8 s0 = *(const bf16x8*)&sS[(wm+l15)*72+kf];
      bf16x8 s1 = *(const bf16x8*)&sS[(wm+16+l15)*72+kf];
      bf16x8 w0 = *(const bf16x8*)&sBwT[(wm+l15)*72+kf];
      bf16x8 w1 = *(const bf16x8*)&sBwT[(wm+16+l15)*72+kf];
      bf16x8 c0 = *(const bf16x8*)&sC[(wm+l15)*72+kf];
      bf16x8 c1 = *(const bf16x8*)&sC[(wm+16+l15)*72+kf];
      bf16x8 h0 = *(const bf16x8*)&sHT[(wn+l15)*72+kf];
      bf16x8 h1 = *(const bf16x8*)&sHT[(wn+16+l15)*72+kf];
      aY[0][0] = __builtin_amdgcn_mfma_f32_16x16x32_bf16(s0,b0,aY[0][0],0,0,0);
      aY[0][1] = __builtin_amdgcn_mfma_f32_16x16x32_bf16(s0,b1,aY[0][1],0,0,0);
      aY[1][0] = __builtin_amdgcn_mfma_f32_16x16x32_bf16(s1,b0,aY[1][0],0,0,0);
      aY[1][1] = __builtin_amdgcn_mfma_f32_16x16x32_bf16(s1,b1,aY[1][1],0,0,0);
      aH[0][0] = __builtin_amdgcn_mfma_f32_16x16x32_bf16(w0,b0,aH[0][0],0,0,0);
      aH[0][1] = __builtin_amdgcn_mfma_f32_16x16x32_bf16(w0,b1,aH[0][1],0,0,0);
      aH[1][0] = __builtin_amdgcn_mfma_f32_16x16x32_bf16(w1,b0,aH[1][0],0,0,0);
      aH[1][1] = __builtin_amdgcn_mfma_f32_16x16x32_bf16(w1,b1,aH[1][1],0,0,0);
      aYi[0][0] = __builtin_amdgcn_mfma_f32_16x16x32_bf16(c0,h0,aYi[0][0],0,0,0);
      aYi[0][1] = __builtin_amdgcn_mfma_f32_16x16x32_bf16(c0,h1,aYi[0][1],0,0,0);
      aYi[1][0] = __builtin_amdgcn_mfma_f32_16x16x32_bf16(c1,h0,aYi[1][0],0,0,0);
      aYi[1][1] = __builtin_amdgcn_mfma_f32_16x16x32_bf16(c1,h1,aYi[1][1],0,0,0);
    }

    const float lam = __expf(sCS[t0+63]);
    #pragma unroll
    for (int mi=0;mi<2;++mi)
      #pragma unroll
      for (int ni=0;ni<2;++ni)
        #pragma unroll
        for (int r4=0;r4<4;++r4){
          const int i = wm+mi*16+quad*4+r4;
          const int p = wn+ni*16+l15;
          const float xval = (float)sXT[p*72 + i];
          const float e2 = __expf(sCS[t0+i]);    // <=1 (cs<=0)
          const float yv = aY[mi][ni][r4] + Dh*xval + e2*aYi[mi][ni][r4];
          xy[((size_t)b*SEQ + t0 + i)*DI + h*64 + p] = (__bf16)yv;
          run[mi][ni][r4] = run[mi][ni][r4]*lam + aH[mi][ni][r4];
        }
    __syncthreads();
  }
}

// ---------------------------------------------------------------------------
__global__ __launch_bounds__(256) void gate_rms_k(
    __bf16* __restrict__ y, const __bf16* __restrict__ z, const float* __restrict__ nw)
{
  __shared__ float red[4];
  const int tid = threadIdx.x;
  const int sub = tid>>7;
  const int off = (tid&127)*8;
  const size_t row = (size_t)blockIdx.x*2 + sub;
  __bf16* yrow = y + row*DI;
  const __bf16* zrow = z + row*DI;
  bf16x8 yv = *(const bf16x8*)(yrow+off);
  bf16x8 zv = *(const bf16x8*)(zrow+off);
  float u[8]; float ss = 0.f;
  #pragma unroll
  for (int e=0;e<8;++e){
    float uu = (float)yv[e]*siluf_((float)zv[e]);
    u[e]=uu; ss += uu*uu;
  }
  #pragma unroll
  for (int o=32;o;o>>=1) ss += __shfl_xor(ss,o);
  if ((tid&63)==0) red[tid>>6] = ss;
  __syncthreads();
  ss = red[sub*2] + red[sub*2+1];
  const float sc = rsqrtf(ss*(1.f/DI) + EPSF);
  const float4* nw4 = (const float4*)(nw + off);
  float4 n0 = nw4[0], n1 = nw4[1];
  bf16x8 o;
  #pragma unroll
  for (int e=0;e<8;++e)
    o[e] = (__bf16)(u[e]*sc*(e<4 ? (&n0.x)[e] : (&n1.x)[e-4]));
  *(bf16x8*)(yrow+off) = o;
}

// ---------------------------------------------------------------------------
extern "C" void kernel_launch(void* const* d_in, const int* in_sizes, int n_in,
                              void* d_out, int out_size, void* d_ws, size_t ws_size,
                              hipStream_t stream)
{
  const float* x         = (const float*)d_in[0];
  const float* in_proj_w = (const float*)d_in[1];
  const float* conv_w    = (const float*)d_in[2];
  const float* conv_b    = (const float*)d_in[3];
  const float* dt_bias   = (const float*)d_in[4];
  const float* A_log     = (const float*)d_in[5];
  const float* Dp        = (const float*)d_in[6];
  const float* norm_w    = (const float*)d_in[7];
  const float* out_proj_w= (const float*)d_in[8];
  const float* ln_w      = (const float*)d_in[9];
  const float* ln_b      = (const float*)d_in[10];
  const float* final_w   = (const float*)d_in[11];
  const float* final_b   = (const float*)d_in[12];
  float* out = (float*)d_out;

  const size_t ROWS = (size_t)BATCH*SEQ;        // 16384
  __bf16* wbf_in  = (__bf16*)d_ws;
  __bf16* wbf_out = wbf_in  + (size_t)NL*DPROJ*DM;
  __bf16* wbf_fin = wbf_out + (size_t)NL*DM*DI;
  __bf16* zbuf    = wbf_fin + (size_t)DM*DM;
  __bf16* xbw     = zbuf    + ROWS*DI;
  __bf16* ybuf    = xbw     + ROWS*XBW;
  __bf16* bcb     = ybuf    + ROWS*DI;
  __bf16* xcur    = bcb     + ROWS*128;

  {
    int n1 = NL*DPROJ*DM/4, n2 = NL*DM*DI/4, n3 = DM*DM/4, n4 = (int)(ROWS*DM/4);
    int tot = n1+n2+n3+n4;
    cast4_k<<<(tot+255)/256, 256, 0, stream>>>(
        in_proj_w, wbf_in, n1, out_proj_w, wbf_out, n2,
        final_w, wbf_fin, n3, x, xcur, n4);
  }

  const int convTotal = BATCH*SEQ*CSEG;
  const int BIGN = 1<<30;

  for (int l=0; l<NL; ++l){
    const __bf16* wl = wbf_in + (size_t)l*DPROJ*DM;
    // in_proj: 128x128 gemm128 (row-tile fastest for XCD A-locality)
    gemm128<__bf16><<<dim3((int)(ROWS/128), (DPROJ+127)/128), 256, 0, stream>>>(
        xcur, wl, zbuf, xbw, nullptr, (int)ROWS, DPROJ, DI, XBW, DI, DM, 0);
    conv_silu_k<<<(convTotal+255)/256, 256, 0, stream>>>(
        xbw, conv_w + (size_t)l*CDIM*4, conv_b + (size_t)l*CDIM, ybuf, bcb);
    ssd_fused_k<<<BATCH*NH, 256, 0, stream>>>(
        bcb, ybuf, xbw, dt_bias + l*NH, A_log + l*NH, Dp + l*NH);
    gate_rms_k<<<(int)(ROWS/2), 256, 0, stream>>>(ybuf, zbuf, norm_w + (size_t)l*DI);
    // fused out_proj + residual + LayerNorm -> xcur (in-place)
    gemm_ln_k<<<(int)(ROWS/64), 512, 0, stream>>>(
        ybuf, wbf_out + (size_t)l*DM*DI, xcur, ln_w + l*DM, ln_b + l*DM);
  }
  // final head: A-rows remapped to the last PREDN timesteps of xcur
  gemm128<float><<<dim3((BATCH*PREDN)/128, DM/128), 256, 0, stream>>>(
      xcur, wbf_fin, out, out, final_b, BATCH*PREDN, DM, DM, DM, BIGN, DM, 1);
}